// Round 4
// baseline (1118.482 us; speedup 1.0000x reference)
//
#include <hip/hip_runtime.h>
#include <stdint.h>

#define D 128

typedef __attribute__((ext_vector_type(8))) __bf16 bf16x8;
typedef __attribute__((ext_vector_type(4))) __bf16 bf16x4;
typedef __attribute__((ext_vector_type(4))) float f32x4;

// ---------------------------------------------------------------------------
// edge_index dtype detection (int64 per reference vs int32 from x64-disabled JAX)
__global__ void detect_idx(const void* ei, int* flag, int n_nodes) {
    if (blockIdx.x == 0 && threadIdx.x == 0) {
        const long long* p = (const long long*)ei;
        int is64 = 1;
        for (int i = 0; i < 64; ++i) {
            long long v = p[i];
            if (v < 0 || v >= (long long)n_nodes) { is64 = 0; break; }
        }
        *flag = is64;
    }
}

__global__ void convert_idx(const void* ei, const int* flag,
                            int* src32, int* dst32, int nE) {
    int e = blockIdx.x * blockDim.x + threadIdx.x;
    if (e >= nE) return;
    if (*flag) {
        const long long* p = (const long long*)ei;
        src32[e] = (int)p[e];
        dst32[e] = (int)p[(size_t)nE + e];
    } else {
        const int* p = (const int*)ei;
        src32[e] = p[e];
        dst32[e] = p[nE + e];
    }
}

// ---------------------------------------------------------------------------
// CSR build (by dst), reused across all 3 layers
__global__ void hist_kernel(const int* dst32, int* counts, int nE) {
    int e = blockIdx.x * blockDim.x + threadIdx.x;
    if (e < nE) atomicAdd(&counts[dst32[e]], 1);
}

__global__ void scan1(const int* counts, int* local_inc, int* bsums, int n) {
    __shared__ int s[1024];
    int i = blockIdx.x * 1024 + threadIdx.x;
    int v = (i < n) ? counts[i] : 0;
    s[threadIdx.x] = v;
    __syncthreads();
    for (int off = 1; off < 1024; off <<= 1) {
        int t = 0;
        if ((int)threadIdx.x >= off) t = s[threadIdx.x - off];
        __syncthreads();
        if ((int)threadIdx.x >= off) s[threadIdx.x] += t;
        __syncthreads();
    }
    if (i < n) local_inc[i] = s[threadIdx.x];
    if (threadIdx.x == 1023) bsums[blockIdx.x] = s[1023];
}

// parallel exclusive scan of block sums (nb <= 1024) — replaces serial scan2
__global__ void scan2p(int* bsums, int nb) {
    __shared__ int s[1024];
    int t = threadIdx.x;
    int v = (t < nb) ? bsums[t] : 0;
    s[t] = v;
    __syncthreads();
    for (int off = 1; off < 1024; off <<= 1) {
        int u = 0;
        if (t >= off) u = s[t - off];
        __syncthreads();
        if (t >= off) s[t] += u;
        __syncthreads();
    }
    if (t < nb) bsums[t] = s[t] - v;   // exclusive
}

__global__ void scan3(const int* local_inc, const int* counts, const int* bsums,
                      int* offsets, int n, int nE) {
    int i = blockIdx.x * blockDim.x + threadIdx.x;
    if (i < n) offsets[i] = local_inc[i] - counts[i] + bsums[i >> 10];
    if (i == 0) offsets[n] = nE;
}

__global__ void fill_csr(const int* src32, const int* dst32, const int* offsets,
                         int* cursor, int* csr_src, int nE) {
    int e = blockIdx.x * blockDim.x + threadIdx.x;
    if (e < nE) {
        int d = dst32[e];
        int pos = offsets[d] + atomicAdd(&cursor[d], 1);
        csr_src[pos] = src32[e];
    }
}

// ---------------------------------------------------------------------------
// degree counting-sort: perm lists nodes in ascending-degree order so the
// 4 nodes sharing a wave in agg_mean4 have equal trip counts (no divergence).
__global__ void deg_hist(const int* counts, int* dhist, int n) {
    int i = blockIdx.x * 256 + threadIdx.x;
    if (i < n) {
        int d = counts[i]; if (d > 255) d = 255;
        atomicAdd(&dhist[d], 1);
    }
}

__global__ void deg_scan(int* dhist) {   // 1 block, 256 threads -> exclusive
    __shared__ int s[256];
    int t = threadIdx.x;
    int v = dhist[t];
    s[t] = v;
    __syncthreads();
    for (int off = 1; off < 256; off <<= 1) {
        int u = 0;
        if (t >= off) u = s[t - off];
        __syncthreads();
        if (t >= off) s[t] += u;
        __syncthreads();
    }
    dhist[t] = s[t] - v;
}

__global__ void deg_scatter(const int* counts, const int* dbase, int* dcur,
                            int* perm, int n) {
    int i = blockIdx.x * 256 + threadIdx.x;
    if (i < n) {
        int d = counts[i]; if (d > 255) d = 255;
        int pos = dbase[d] + atomicAdd(&dcur[d], 1);
        perm[pos] = i;
    }
}

// ---------------------------------------------------------------------------
// W preprocessing: stacked [Wl;Wr] transposed to [col][k], split bf16 hi/lo.
__global__ void build_wt(const float* __restrict__ Wa, const float* __restrict__ Wr,
                         __bf16* __restrict__ WtHi, __bf16* __restrict__ WtLo) {
    int idx = blockIdx.x * 256 + threadIdx.x;         // 3*128*256 total
    if (idx >= 3 * 128 * 256) return;
    int L = idx / (128 * 256);
    int rem = idx % (128 * 256);
    int c = rem / 256;
    int k = rem % 256;
    float v = (k < 128) ? Wa[((size_t)L * 128 + k) * 128 + c]
                        : Wr[((size_t)L * 128 + (k - 128)) * 128 + c];
    __bf16 h = (__bf16)v;
    __bf16 l = (__bf16)(v - (float)h);
    WtHi[idx] = h;
    WtLo[idx] = l;
}

// ---------------------------------------------------------------------------
// x fp32 -> bf16 hi/lo planes (once, layer-0 input)
__global__ void split_x(const float* __restrict__ x, __bf16* __restrict__ aHi,
                        __bf16* __restrict__ aLo, int total8) {
    int i = blockIdx.x * 256 + threadIdx.x;           // 8 floats per thread
    if (i >= total8) return;
    const float4* p = (const float4*)(x + (size_t)i * 8);
    float4 v0 = p[0], v1 = p[1];
    float vv[8] = {v0.x, v0.y, v0.z, v0.w, v1.x, v1.y, v1.z, v1.w};
    bf16x8 h, l;
    #pragma unroll
    for (int j = 0; j < 8; ++j) {
        __bf16 hh = (__bf16)vv[j];
        h[j] = hh;
        l[j] = (__bf16)(vv[j] - (float)hh);
    }
    *(bf16x8*)(aHi + (size_t)i * 8) = h;
    *(bf16x8*)(aLo + (size_t)i * 8) = l;
}

// ---------------------------------------------------------------------------
// mean aggregation v4: degree-sorted node order (perm) kills wave divergence.
// One node per 16-lane group (bf16x8 = 16B/lane), 4x unrolled row gathers.
__global__ __launch_bounds__(256) void agg_mean4(
        const __bf16* __restrict__ aHi, const int* __restrict__ csr,
        const int* __restrict__ offs, const int* __restrict__ perm,
        __bf16* __restrict__ mHi, __bf16* __restrict__ mLo, int n) {
    int g = (blockIdx.x * blockDim.x + threadIdx.x) >> 4;
    int l8 = (threadIdx.x & 15) << 3;
    if (g >= n) return;
    int node = perm[g];
    int beg = offs[node], end = offs[node + 1];
    float acc[8] = {0.f, 0.f, 0.f, 0.f, 0.f, 0.f, 0.f, 0.f};
    int i = beg;
    for (; i + 4 <= end; i += 4) {
        int s0 = csr[i], s1 = csr[i + 1], s2 = csr[i + 2], s3 = csr[i + 3];
        bf16x8 v0 = *(const bf16x8*)(aHi + (size_t)s0 * D + l8);
        bf16x8 v1 = *(const bf16x8*)(aHi + (size_t)s1 * D + l8);
        bf16x8 v2 = *(const bf16x8*)(aHi + (size_t)s2 * D + l8);
        bf16x8 v3 = *(const bf16x8*)(aHi + (size_t)s3 * D + l8);
        #pragma unroll
        for (int j = 0; j < 8; ++j)
            acc[j] += (float)v0[j] + (float)v1[j] + (float)v2[j] + (float)v3[j];
    }
    for (; i < end; ++i) {
        int s = csr[i];
        bf16x8 v = *(const bf16x8*)(aHi + (size_t)s * D + l8);
        #pragma unroll
        for (int j = 0; j < 8; ++j) acc[j] += (float)v[j];
    }
    int deg = end - beg;
    float inv = 1.0f / (float)(deg > 1 ? deg : 1);
    bf16x8 h, l;
    #pragma unroll
    for (int j = 0; j < 8; ++j) {
        float m = acc[j] * inv;
        __bf16 hh = (__bf16)m;
        h[j] = hh;
        l[j] = (__bf16)(m - (float)hh);
    }
    *(bf16x8*)(mHi + (size_t)node * D + l8) = h;
    *(bf16x8*)(mLo + (size_t)node * D + l8) = l;
}

// ---------------------------------------------------------------------------
// MFMA GEMM v4: B-fragments resident in VGPRs (W is 128KB/layer), grid-stride
// over 16-row tiles. Wave w owns cols w*32..w*32+31 (2 col-tiles); all 4 waves
// share the tile's 16 rows. Operand-swapped MFMA: mfma(Wfrag, actfrag) puts
// one output ROW per lane (lane&15) and 4 consecutive COLS (kg*4+reg) per acc
// register -> contiguous 8B/16B stores. One __syncthreads per tile orders all
// waves' full-K A-loads before any in-place col-slice store (out==act planes).
// acc += wh*ah + wl*ah + wh*al  (== ah*wh + ah*wl + al*wh).
__global__ __launch_bounds__(256, 2) void sage_gemm4(
        const __bf16* __restrict__ mHi, const __bf16* __restrict__ mLo,
        const __bf16* __restrict__ aHi, const __bf16* __restrict__ aLo,
        const __bf16* __restrict__ WtHi, const __bf16* __restrict__ WtLo,
        const float* __restrict__ bias,
        __bf16* oHi, __bf16* oLo, float* oF,
        int n, int mode, int ntiles) {
    int tid  = threadIdx.x;
    int wave = tid >> 6;
    int lane = tid & 63;
    int r16  = lane & 15;
    int kg   = lane >> 4;

    bf16x8 zero;
    #pragma unroll
    for (int j = 0; j < 8; ++j) zero[j] = (__bf16)0.f;

    // B fragments for this wave's 2 col-tiles: resident across all tiles.
    // chunk c8: 0-3 = mean-half (k 0..127 of stacked 256), 4-7 = act-half.
    bf16x8 BH[8][2], BL[8][2];
    #pragma unroll
    for (int c8 = 0; c8 < 8; ++c8) {
        #pragma unroll
        for (int q = 0; q < 2; ++q) {
            int col = (wave * 2 + q) * 16 + r16;
            size_t o = (size_t)col * 256 + c8 * 32 + kg * 8;
            BH[c8][q] = *(const bf16x8*)(WtHi + o);
            BL[c8][q] = *(const bf16x8*)(WtLo + o);
        }
    }
    float4 bv[2];
    #pragma unroll
    for (int q = 0; q < 2; ++q)
        bv[q] = *(const float4*)(bias + (wave * 2 + q) * 16 + kg * 4);

    for (int t = blockIdx.x; t < ntiles; t += gridDim.x) {
        int row = t * 16 + r16;
        bool valid = row < n;

        // all A fragments for this tile (full K, mean then act halves)
        bf16x8 AH[8], AL[8];
        #pragma unroll
        for (int c8 = 0; c8 < 8; ++c8) {
            const __bf16* hi = (c8 < 4) ? mHi : aHi;
            const __bf16* lo = (c8 < 4) ? mLo : aLo;
            int k0 = (c8 & 3) * 32 + kg * 8;
            if (valid) {
                AH[c8] = *(const bf16x8*)(hi + (size_t)row * D + k0);
                AL[c8] = *(const bf16x8*)(lo + (size_t)row * D + k0);
            } else { AH[c8] = zero; AL[c8] = zero; }
        }
        __syncthreads();   // every wave's A-loads done before any store below

        f32x4 acc[2];
        acc[0] = (f32x4){0.f, 0.f, 0.f, 0.f};
        acc[1] = (f32x4){0.f, 0.f, 0.f, 0.f};
        #pragma unroll
        for (int c8 = 0; c8 < 8; ++c8) {
            #pragma unroll
            for (int q = 0; q < 2; ++q) {
                acc[q] = __builtin_amdgcn_mfma_f32_16x16x32_bf16(BH[c8][q], AH[c8], acc[q], 0, 0, 0);
                acc[q] = __builtin_amdgcn_mfma_f32_16x16x32_bf16(BL[c8][q], AH[c8], acc[q], 0, 0, 0);
                acc[q] = __builtin_amdgcn_mfma_f32_16x16x32_bf16(BH[c8][q], AL[c8], acc[q], 0, 0, 0);
            }
        }

        if (valid) {
            #pragma unroll
            for (int q = 0; q < 2; ++q) {
                int col0 = (wave * 2 + q) * 16 + kg * 4;
                float v0 = acc[q][0] + bv[q].x;
                float v1 = acc[q][1] + bv[q].y;
                float v2 = acc[q][2] + bv[q].z;
                float v3 = acc[q][3] + bv[q].w;
                if (mode == 0) {
                    v0 = fmaxf(v0, 0.f); v1 = fmaxf(v1, 0.f);
                    v2 = fmaxf(v2, 0.f); v3 = fmaxf(v3, 0.f);
                    bf16x4 h4, l4;
                    float vv[4] = {v0, v1, v2, v3};
                    #pragma unroll
                    for (int j = 0; j < 4; ++j) {
                        __bf16 hh = (__bf16)vv[j];
                        h4[j] = hh;
                        l4[j] = (__bf16)(vv[j] - (float)hh);
                    }
                    *(bf16x4*)(oHi + (size_t)row * D + col0) = h4;
                    *(bf16x4*)(oLo + (size_t)row * D + col0) = l4;
                } else {
                    float4 o = make_float4(v0, v1, v2, v3);
                    *(float4*)(oF + (size_t)row * D + col0) = o;
                }
            }
        }
    }
}

// ---------------------------------------------------------------------------
extern "C" void kernel_launch(void* const* d_in, const int* in_sizes, int n_in,
                              void* d_out, int out_size, void* d_ws, size_t ws_size,
                              hipStream_t stream) {
    const float* x  = (const float*)d_in[0];
    const void*  ei = d_in[1];
    const float* Wa = (const float*)d_in[2];   // [3,128,128]
    const float* Wr = (const float*)d_in[3];   // [3,128,128]
    const float* bb = (const float*)d_in[4];   // [3,128]
    float* outp = (float*)d_out;

    int n  = in_sizes[0] / D;          // 100000
    int nE = in_sizes[1] / 2;          // 1600000

    char* ws = (char*)d_ws;
    size_t off = 0;
    auto alloc = [&](size_t bytes) -> char* {
        char* p = ws + off;
        off = (off + bytes + 255) & ~(size_t)255;
        return p;
    };
    int* flag      = (int*)alloc(4);
    int* src32     = (int*)alloc((size_t)nE * 4);
    int* dst32     = (int*)alloc((size_t)nE * 4);
    int* counts    = (int*)alloc((size_t)n * 4);
    int* offsets   = (int*)alloc(((size_t)n + 1) * 4);
    int* cursor    = (int*)alloc((size_t)n * 4);
    int* local_inc = (int*)alloc((size_t)n * 4);
    int* bsums     = (int*)alloc(4096);
    int* csr_src   = (int*)alloc((size_t)nE * 4);
    int* perm      = (int*)alloc((size_t)n * 4);
    int* dhist     = (int*)alloc(1024);
    int* dcur      = (int*)alloc(1024);
    __bf16* actHi  = (__bf16*)alloc((size_t)n * D * 2);
    __bf16* actLo  = (__bf16*)alloc((size_t)n * D * 2);
    __bf16* mHi    = (__bf16*)alloc((size_t)n * D * 2);
    __bf16* mLo    = (__bf16*)alloc((size_t)n * D * 2);
    __bf16* WtHi   = (__bf16*)alloc((size_t)3 * 128 * 256 * 2);
    __bf16* WtLo   = (__bf16*)alloc((size_t)3 * 128 * 256 * 2);
    (void)ws_size; (void)n_in; (void)out_size;

    const int B = 256;
    int ge = (nE + B - 1) / B;
    int nb = (n + 1023) / 1024;
    int gn = (n + B - 1) / B;

    // 1) index probe + conversion + W transpose/split + x split
    hipLaunchKernelGGL(detect_idx, dim3(1), dim3(64), 0, stream, ei, flag, n);
    hipLaunchKernelGGL(convert_idx, dim3(ge), dim3(B), 0, stream,
                       ei, flag, src32, dst32, nE);
    hipLaunchKernelGGL(build_wt, dim3(384), dim3(256), 0, stream, Wa, Wr, WtHi, WtLo);
    int total8 = n * D / 8;
    hipLaunchKernelGGL(split_x, dim3((total8 + 255) / 256), dim3(256), 0, stream,
                       x, actHi, actLo, total8);

    // 2) CSR build
    hipMemsetAsync(counts, 0, (size_t)n * 4, stream);
    hipMemsetAsync(cursor, 0, (size_t)n * 4, stream);
    hipMemsetAsync(dhist, 0, 1024, stream);
    hipMemsetAsync(dcur, 0, 1024, stream);
    hipLaunchKernelGGL(hist_kernel, dim3(ge), dim3(B), 0, stream, dst32, counts, nE);
    hipLaunchKernelGGL(scan1, dim3(nb), dim3(1024), 0, stream,
                       counts, local_inc, bsums, n);
    hipLaunchKernelGGL(scan2p, dim3(1), dim3(1024), 0, stream, bsums, nb);
    hipLaunchKernelGGL(scan3, dim3(gn), dim3(B), 0, stream,
                       local_inc, counts, bsums, offsets, n, nE);
    hipLaunchKernelGGL(fill_csr, dim3(ge), dim3(B), 0, stream,
                       src32, dst32, offsets, cursor, csr_src, nE);

    // 2b) degree counting-sort -> perm (ascending degree)
    hipLaunchKernelGGL(deg_hist, dim3(gn), dim3(B), 0, stream, counts, dhist, n);
    hipLaunchKernelGGL(deg_scan, dim3(1), dim3(256), 0, stream, dhist);
    hipLaunchKernelGGL(deg_scatter, dim3(gn), dim3(B), 0, stream,
                       counts, dhist, dcur, perm, n);

    // 3) layers
    int agg_blocks = (n * 16 + B - 1) / B;
    int ntiles = (n + 15) / 16;
    int gemm_grid = 512;               // 2 blocks/CU at launch_bounds(256,2)
    const int WSTRIDE = 128 * 256;

    // layer 0 (ReLU)
    hipLaunchKernelGGL(agg_mean4, dim3(agg_blocks), dim3(B), 0, stream,
                       actHi, csr_src, offsets, perm, mHi, mLo, n);
    hipLaunchKernelGGL(sage_gemm4, dim3(gemm_grid), dim3(B), 0, stream,
                       mHi, mLo, actHi, actLo, WtHi + 0 * WSTRIDE, WtLo + 0 * WSTRIDE,
                       bb + 0 * D, actHi, actLo, outp, n, 0, ntiles);

    // layer 1 (ReLU)
    hipLaunchKernelGGL(agg_mean4, dim3(agg_blocks), dim3(B), 0, stream,
                       actHi, csr_src, offsets, perm, mHi, mLo, n);
    hipLaunchKernelGGL(sage_gemm4, dim3(gemm_grid), dim3(B), 0, stream,
                       mHi, mLo, actHi, actLo, WtHi + 1 * WSTRIDE, WtLo + 1 * WSTRIDE,
                       bb + 1 * D, actHi, actLo, outp, n, 0, ntiles);

    // layer 2 (no ReLU, fp32 out)
    hipLaunchKernelGGL(agg_mean4, dim3(agg_blocks), dim3(B), 0, stream,
                       actHi, csr_src, offsets, perm, mHi, mLo, n);
    hipLaunchKernelGGL(sage_gemm4, dim3(gemm_grid), dim3(B), 0, stream,
                       mHi, mLo, actHi, actLo, WtHi + 2 * WSTRIDE, WtLo + 2 * WSTRIDE,
                       bb + 2 * D, actHi, actLo, outp, n, 1, ntiles);
}

// Round 5
// 841.747 us; speedup vs baseline: 1.3288x; 1.3288x over previous
//
#include <hip/hip_runtime.h>
#include <stdint.h>

#define D 128

typedef __attribute__((ext_vector_type(8))) __bf16 bf16x8;
typedef __attribute__((ext_vector_type(4))) __bf16 bf16x4;
typedef __attribute__((ext_vector_type(4))) float f32x4;

// ---------------------------------------------------------------------------
// edge_index dtype detection (int64 per reference vs int32 from x64-disabled JAX)
__global__ void detect_idx(const void* ei, int* flag, int n_nodes) {
    if (blockIdx.x == 0 && threadIdx.x == 0) {
        const long long* p = (const long long*)ei;
        int is64 = 1;
        for (int i = 0; i < 64; ++i) {
            long long v = p[i];
            if (v < 0 || v >= (long long)n_nodes) { is64 = 0; break; }
        }
        *flag = is64;
    }
}

__global__ void convert_idx(const void* ei, const int* flag,
                            int* src32, int* dst32, int nE) {
    int e = blockIdx.x * blockDim.x + threadIdx.x;
    if (e >= nE) return;
    if (*flag) {
        const long long* p = (const long long*)ei;
        src32[e] = (int)p[e];
        dst32[e] = (int)p[(size_t)nE + e];
    } else {
        const int* p = (const int*)ei;
        src32[e] = p[e];
        dst32[e] = p[nE + e];
    }
}

// ---------------------------------------------------------------------------
// CSR build (by dst), reused across all 3 layers
__global__ void hist_kernel(const int* dst32, int* counts, int nE) {
    int e = blockIdx.x * blockDim.x + threadIdx.x;
    if (e < nE) atomicAdd(&counts[dst32[e]], 1);
}

__global__ void scan1(const int* counts, int* local_inc, int* bsums, int n) {
    __shared__ int s[1024];
    int i = blockIdx.x * 1024 + threadIdx.x;
    int v = (i < n) ? counts[i] : 0;
    s[threadIdx.x] = v;
    __syncthreads();
    for (int off = 1; off < 1024; off <<= 1) {
        int t = 0;
        if ((int)threadIdx.x >= off) t = s[threadIdx.x - off];
        __syncthreads();
        if ((int)threadIdx.x >= off) s[threadIdx.x] += t;
        __syncthreads();
    }
    if (i < n) local_inc[i] = s[threadIdx.x];
    if (threadIdx.x == 1023) bsums[blockIdx.x] = s[1023];
}

// parallel exclusive scan of block sums (nb <= 1024)
__global__ void scan2p(int* bsums, int nb) {
    __shared__ int s[1024];
    int t = threadIdx.x;
    int v = (t < nb) ? bsums[t] : 0;
    s[t] = v;
    __syncthreads();
    for (int off = 1; off < 1024; off <<= 1) {
        int u = 0;
        if (t >= off) u = s[t - off];
        __syncthreads();
        if (t >= off) s[t] += u;
        __syncthreads();
    }
    if (t < nb) bsums[t] = s[t] - v;   // exclusive
}

__global__ void scan3(const int* local_inc, const int* counts, const int* bsums,
                      int* offsets, int n, int nE) {
    int i = blockIdx.x * blockDim.x + threadIdx.x;
    if (i < n) offsets[i] = local_inc[i] - counts[i] + bsums[i >> 10];
    if (i == 0) offsets[n] = nE;
}

__global__ void fill_csr(const int* src32, const int* dst32, const int* offsets,
                         int* cursor, int* csr_src, int nE) {
    int e = blockIdx.x * blockDim.x + threadIdx.x;
    if (e < nE) {
        int d = dst32[e];
        int pos = offsets[d] + atomicAdd(&cursor[d], 1);
        csr_src[pos] = src32[e];
    }
}

// ---------------------------------------------------------------------------
// W preprocessing: stacked [Wl;Wr] transposed to [col][k], split bf16 hi/lo.
__global__ void build_wt(const float* __restrict__ Wa, const float* __restrict__ Wr,
                         __bf16* __restrict__ WtHi, __bf16* __restrict__ WtLo) {
    int idx = blockIdx.x * 256 + threadIdx.x;         // 3*128*256 total
    if (idx >= 3 * 128 * 256) return;
    int L = idx / (128 * 256);
    int rem = idx % (128 * 256);
    int c = rem / 256;
    int k = rem % 256;
    float v = (k < 128) ? Wa[((size_t)L * 128 + k) * 128 + c]
                        : Wr[((size_t)L * 128 + (k - 128)) * 128 + c];
    __bf16 h = (__bf16)v;
    __bf16 l = (__bf16)(v - (float)h);
    WtHi[idx] = h;
    WtLo[idx] = l;
}

// ---------------------------------------------------------------------------
// x fp32 -> bf16 hi/lo planes (once, layer-0 input)
__global__ void split_x(const float* __restrict__ x, __bf16* __restrict__ aHi,
                        __bf16* __restrict__ aLo, int total8) {
    int i = blockIdx.x * 256 + threadIdx.x;           // 8 floats per thread
    if (i >= total8) return;
    const float4* p = (const float4*)(x + (size_t)i * 8);
    float4 v0 = p[0], v1 = p[1];
    float vv[8] = {v0.x, v0.y, v0.z, v0.w, v1.x, v1.y, v1.z, v1.w};
    bf16x8 h, l;
    #pragma unroll
    for (int j = 0; j < 8; ++j) {
        __bf16 hh = (__bf16)vv[j];
        h[j] = hh;
        l[j] = (__bf16)(vv[j] - (float)hh);
    }
    *(bf16x8*)(aHi + (size_t)i * 8) = h;
    *(bf16x8*)(aLo + (size_t)i * 8) = l;
}

// ---------------------------------------------------------------------------
// mean aggregation: gather bf16 HI plane only (256B/row). One node per
// 16-lane group (bf16x8 = 16B/lane), 4x unrolled independent row gathers.
__global__ __launch_bounds__(256) void agg_mean3(
        const __bf16* __restrict__ aHi, const int* __restrict__ csr,
        const int* __restrict__ offs, __bf16* __restrict__ mHi,
        __bf16* __restrict__ mLo, int n) {
    int node = (blockIdx.x * blockDim.x + threadIdx.x) >> 4;
    int l8 = (threadIdx.x & 15) << 3;
    if (node >= n) return;
    int beg = offs[node], end = offs[node + 1];
    float acc[8] = {0.f, 0.f, 0.f, 0.f, 0.f, 0.f, 0.f, 0.f};
    int i = beg;
    for (; i + 4 <= end; i += 4) {
        int s0 = csr[i], s1 = csr[i + 1], s2 = csr[i + 2], s3 = csr[i + 3];
        bf16x8 v0 = *(const bf16x8*)(aHi + (size_t)s0 * D + l8);
        bf16x8 v1 = *(const bf16x8*)(aHi + (size_t)s1 * D + l8);
        bf16x8 v2 = *(const bf16x8*)(aHi + (size_t)s2 * D + l8);
        bf16x8 v3 = *(const bf16x8*)(aHi + (size_t)s3 * D + l8);
        #pragma unroll
        for (int j = 0; j < 8; ++j)
            acc[j] += (float)v0[j] + (float)v1[j] + (float)v2[j] + (float)v3[j];
    }
    for (; i < end; ++i) {
        int s = csr[i];
        bf16x8 v = *(const bf16x8*)(aHi + (size_t)s * D + l8);
        #pragma unroll
        for (int j = 0; j < 8; ++j) acc[j] += (float)v[j];
    }
    int deg = end - beg;
    float inv = 1.0f / (float)(deg > 1 ? deg : 1);
    bf16x8 h, l;
    #pragma unroll
    for (int j = 0; j < 8; ++j) {
        float m = acc[j] * inv;
        __bf16 hh = (__bf16)m;
        h[j] = hh;
        l[j] = (__bf16)(m - (float)hh);
    }
    *(bf16x8*)(mHi + (size_t)node * D + l8) = h;
    *(bf16x8*)(mLo + (size_t)node * D + l8) = l;
}

// ---------------------------------------------------------------------------
// MFMA GEMM v5: full W (hi+lo, 128KB) staged into LDS once, XOR-swizzled
// (k_byte ^= (col&7)<<4 within each col's 512B row -> each 8-lane LDS phase
// hits 8 distinct 16B slots, conflict-free). After one barrier, each wave
// independently grid-strides over 16-row tiles: A-loads for its OWN rows
// (prefetched one tile ahead), 128 ds_read_b128 + 192 MFMA per tile, no
// further syncthreads. Operand-swapped mfma(Wfrag, Afrag) -> lane r16 = out
// row, kg*4+reg = out col (verified in R4). In-place safe: a wave reads and
// writes only its own tiles' rows.
__global__ __launch_bounds__(256, 1) void sage_gemm5(
        const __bf16* __restrict__ mHi, const __bf16* __restrict__ mLo,
        const __bf16* __restrict__ aHi, const __bf16* __restrict__ aLo,
        const __bf16* __restrict__ WtHi, const __bf16* __restrict__ WtLo,
        const float* __restrict__ bias,
        __bf16* oHi, __bf16* oLo, float* oF,
        int n, int mode, int ntiles) {
    __shared__ __align__(16) char sW[131072];   // [plane:64KB][col:512B][k swz]
    int tid = threadIdx.x;

    // stage W: 8192 x 16B chunks
    for (int c = tid; c < 8192; c += 256) {
        int plane = c >> 12;
        int rem = c & 4095;
        int col = rem >> 5;          // 32 chunks of 16B per col
        int kc  = rem & 31;
        const __bf16* src = (plane ? WtLo : WtHi) + (size_t)col * 256 + kc * 8;
        int dst = (plane << 16) + col * 512 + ((kc * 16) ^ ((col & 7) << 4));
        *(int4*)(sW + dst) = *(const int4*)src;
    }
    __syncthreads();

    int wave = tid >> 6;
    int lane = tid & 63;
    int r16  = lane & 15;
    int kg   = lane >> 4;
    int wid     = blockIdx.x * 4 + wave;
    int wstride = gridDim.x * 4;
    int xm = (r16 & 7) << 4;

    // per-lane swizzled LDS k-offsets (hi plane; lo = +65536; col-tile q adds q*8192)
    int kb[8];
    #pragma unroll
    for (int c8 = 0; c8 < 8; ++c8)
        kb[c8] = r16 * 512 + ((c8 * 64 + kg * 16) ^ xm);

    float4 bv[8];
    #pragma unroll
    for (int q = 0; q < 8; ++q)
        bv[q] = *(const float4*)(bias + q * 16 + kg * 4);

    bf16x8 zero;
    #pragma unroll
    for (int j = 0; j < 8; ++j) zero[j] = (__bf16)0.f;

    bf16x8 AH[8], AL[8], NH[8], NL[8];

    // initial A load for first tile
    {
        int row = wid * 16 + r16;
        bool v = (wid < ntiles) && (row < n);
        #pragma unroll
        for (int c8 = 0; c8 < 8; ++c8) {
            const __bf16* hi = (c8 < 4) ? mHi : aHi;
            const __bf16* lo = (c8 < 4) ? mLo : aLo;
            size_t o = (size_t)row * D + (c8 & 3) * 32 + kg * 8;
            AH[c8] = v ? *(const bf16x8*)(hi + o) : zero;
            AL[c8] = v ? *(const bf16x8*)(lo + o) : zero;
        }
    }

    for (int t = wid; t < ntiles; t += wstride) {
        // prefetch next tile's A (this wave's own future rows — no hazard)
        {
            int tn = t + wstride;
            int row = tn * 16 + r16;
            bool v = (tn < ntiles) && (row < n);
            #pragma unroll
            for (int c8 = 0; c8 < 8; ++c8) {
                const __bf16* hi = (c8 < 4) ? mHi : aHi;
                const __bf16* lo = (c8 < 4) ? mLo : aLo;
                size_t o = (size_t)row * D + (c8 & 3) * 32 + kg * 8;
                NH[c8] = v ? *(const bf16x8*)(hi + o) : zero;
                NL[c8] = v ? *(const bf16x8*)(lo + o) : zero;
            }
        }

        f32x4 acc[8];
        #pragma unroll
        for (int q = 0; q < 8; ++q) acc[q] = (f32x4){0.f, 0.f, 0.f, 0.f};

        #pragma unroll
        for (int c8 = 0; c8 < 8; ++c8) {
            #pragma unroll
            for (int q = 0; q < 8; ++q) {
                bf16x8 bh = *(const bf16x8*)(sW + q * 8192 + kb[c8]);
                bf16x8 bl = *(const bf16x8*)(sW + 65536 + q * 8192 + kb[c8]);
                acc[q] = __builtin_amdgcn_mfma_f32_16x16x32_bf16(bh, AH[c8], acc[q], 0, 0, 0);
                acc[q] = __builtin_amdgcn_mfma_f32_16x16x32_bf16(bl, AH[c8], acc[q], 0, 0, 0);
                acc[q] = __builtin_amdgcn_mfma_f32_16x16x32_bf16(bh, AL[c8], acc[q], 0, 0, 0);
            }
        }

        int row = t * 16 + r16;
        if (row < n) {
            #pragma unroll
            for (int q = 0; q < 8; ++q) {
                int col0 = q * 16 + kg * 4;
                float v0 = acc[q][0] + bv[q].x;
                float v1 = acc[q][1] + bv[q].y;
                float v2 = acc[q][2] + bv[q].z;
                float v3 = acc[q][3] + bv[q].w;
                if (mode == 0) {
                    v0 = fmaxf(v0, 0.f); v1 = fmaxf(v1, 0.f);
                    v2 = fmaxf(v2, 0.f); v3 = fmaxf(v3, 0.f);
                    float vv[4] = {v0, v1, v2, v3};
                    bf16x4 h4, l4;
                    #pragma unroll
                    for (int j = 0; j < 4; ++j) {
                        __bf16 hh = (__bf16)vv[j];
                        h4[j] = hh;
                        l4[j] = (__bf16)(vv[j] - (float)hh);
                    }
                    *(bf16x4*)(oHi + (size_t)row * D + col0) = h4;
                    *(bf16x4*)(oLo + (size_t)row * D + col0) = l4;
                } else {
                    *(float4*)(oF + (size_t)row * D + col0) =
                        make_float4(v0, v1, v2, v3);
                }
            }
        }

        #pragma unroll
        for (int c8 = 0; c8 < 8; ++c8) { AH[c8] = NH[c8]; AL[c8] = NL[c8]; }
    }
}

// ---------------------------------------------------------------------------
extern "C" void kernel_launch(void* const* d_in, const int* in_sizes, int n_in,
                              void* d_out, int out_size, void* d_ws, size_t ws_size,
                              hipStream_t stream) {
    const float* x  = (const float*)d_in[0];
    const void*  ei = d_in[1];
    const float* Wa = (const float*)d_in[2];   // [3,128,128]
    const float* Wr = (const float*)d_in[3];   // [3,128,128]
    const float* bb = (const float*)d_in[4];   // [3,128]
    float* outp = (float*)d_out;

    int n  = in_sizes[0] / D;          // 100000
    int nE = in_sizes[1] / 2;          // 1600000

    char* ws = (char*)d_ws;
    size_t off = 0;
    auto alloc = [&](size_t bytes) -> char* {
        char* p = ws + off;
        off = (off + bytes + 255) & ~(size_t)255;
        return p;
    };
    int* flag      = (int*)alloc(4);
    int* src32     = (int*)alloc((size_t)nE * 4);
    int* dst32     = (int*)alloc((size_t)nE * 4);
    int* counts    = (int*)alloc((size_t)n * 4);
    int* offsets   = (int*)alloc(((size_t)n + 1) * 4);
    int* cursor    = (int*)alloc((size_t)n * 4);
    int* local_inc = (int*)alloc((size_t)n * 4);
    int* bsums     = (int*)alloc(4096);
    int* csr_src   = (int*)alloc((size_t)nE * 4);
    __bf16* actHi  = (__bf16*)alloc((size_t)n * D * 2);
    __bf16* actLo  = (__bf16*)alloc((size_t)n * D * 2);
    __bf16* mHi    = (__bf16*)alloc((size_t)n * D * 2);
    __bf16* mLo    = (__bf16*)alloc((size_t)n * D * 2);
    __bf16* WtHi   = (__bf16*)alloc((size_t)3 * 128 * 256 * 2);
    __bf16* WtLo   = (__bf16*)alloc((size_t)3 * 128 * 256 * 2);
    (void)ws_size; (void)n_in; (void)out_size;

    const int B = 256;
    int ge = (nE + B - 1) / B;
    int nb = (n + 1023) / 1024;
    int gn = (n + B - 1) / B;

    // 1) index probe + conversion + W transpose/split + x split
    hipLaunchKernelGGL(detect_idx, dim3(1), dim3(64), 0, stream, ei, flag, n);
    hipLaunchKernelGGL(convert_idx, dim3(ge), dim3(B), 0, stream,
                       ei, flag, src32, dst32, nE);
    hipLaunchKernelGGL(build_wt, dim3(384), dim3(256), 0, stream, Wa, Wr, WtHi, WtLo);
    int total8 = n * D / 8;
    hipLaunchKernelGGL(split_x, dim3((total8 + 255) / 256), dim3(256), 0, stream,
                       x, actHi, actLo, total8);

    // 2) CSR build
    hipMemsetAsync(counts, 0, (size_t)n * 4, stream);
    hipMemsetAsync(cursor, 0, (size_t)n * 4, stream);
    hipLaunchKernelGGL(hist_kernel, dim3(ge), dim3(B), 0, stream, dst32, counts, nE);
    hipLaunchKernelGGL(scan1, dim3(nb), dim3(1024), 0, stream,
                       counts, local_inc, bsums, n);
    hipLaunchKernelGGL(scan2p, dim3(1), dim3(1024), 0, stream, bsums, nb);
    hipLaunchKernelGGL(scan3, dim3(gn), dim3(B), 0, stream,
                       local_inc, counts, bsums, offsets, n, nE);
    hipLaunchKernelGGL(fill_csr, dim3(ge), dim3(B), 0, stream,
                       src32, dst32, offsets, cursor, csr_src, nE);

    // 3) layers
    int agg_blocks = (n * 16 + B - 1) / B;
    int ntiles = (n + 15) / 16;
    int gemm_grid = 256;               // 1 block/CU (128KB LDS)
    const int WSTRIDE = 128 * 256;

    // layer 0 (ReLU)
    hipLaunchKernelGGL(agg_mean3, dim3(agg_blocks), dim3(B), 0, stream,
                       actHi, csr_src, offsets, mHi, mLo, n);
    hipLaunchKernelGGL(sage_gemm5, dim3(gemm_grid), dim3(B), 0, stream,
                       mHi, mLo, actHi, actLo, WtHi + 0 * WSTRIDE, WtLo + 0 * WSTRIDE,
                       bb + 0 * D, actHi, actLo, outp, n, 0, ntiles);

    // layer 1 (ReLU)
    hipLaunchKernelGGL(agg_mean3, dim3(agg_blocks), dim3(B), 0, stream,
                       actHi, csr_src, offsets, mHi, mLo, n);
    hipLaunchKernelGGL(sage_gemm5, dim3(gemm_grid), dim3(B), 0, stream,
                       mHi, mLo, actHi, actLo, WtHi + 1 * WSTRIDE, WtLo + 1 * WSTRIDE,
                       bb + 1 * D, actHi, actLo, outp, n, 0, ntiles);

    // layer 2 (no ReLU, fp32 out)
    hipLaunchKernelGGL(agg_mean3, dim3(agg_blocks), dim3(B), 0, stream,
                       actHi, csr_src, offsets, mHi, mLo, n);
    hipLaunchKernelGGL(sage_gemm5, dim3(gemm_grid), dim3(B), 0, stream,
                       mHi, mLo, actHi, actLo, WtHi + 2 * WSTRIDE, WtLo + 2 * WSTRIDE,
                       bb + 2 * D, actHi, actLo, outp, n, 1, ntiles);
}

// Round 6
// 527.767 us; speedup vs baseline: 2.1193x; 1.5949x over previous
//
#include <hip/hip_runtime.h>
#include <stdint.h>

#define D 128

typedef __attribute__((ext_vector_type(8))) __bf16 bf16x8;
typedef __attribute__((ext_vector_type(4))) __bf16 bf16x4;
typedef __attribute__((ext_vector_type(4))) float f32x4;

// ---------------------------------------------------------------------------
// edge_index dtype detection (int64 per reference vs int32 from x64-disabled JAX)
__global__ void detect_idx(const void* ei, int* flag, int n_nodes) {
    if (blockIdx.x == 0 && threadIdx.x == 0) {
        const long long* p = (const long long*)ei;
        int is64 = 1;
        for (int i = 0; i < 64; ++i) {
            long long v = p[i];
            if (v < 0 || v >= (long long)n_nodes) { is64 = 0; break; }
        }
        *flag = is64;
    }
}

__global__ void convert_idx(const void* ei, const int* flag,
                            int* src32, int* dst32, int nE) {
    int e = blockIdx.x * blockDim.x + threadIdx.x;
    if (e >= nE) return;
    if (*flag) {
        const long long* p = (const long long*)ei;
        src32[e] = (int)p[e];
        dst32[e] = (int)p[(size_t)nE + e];
    } else {
        const int* p = (const int*)ei;
        src32[e] = p[e];
        dst32[e] = p[nE + e];
    }
}

// ---------------------------------------------------------------------------
// CSR build (by dst), reused across all 3 layers
__global__ void hist_kernel(const int* dst32, int* counts, int nE) {
    int e = blockIdx.x * blockDim.x + threadIdx.x;
    if (e < nE) atomicAdd(&counts[dst32[e]], 1);
}

__global__ void scan1(const int* counts, int* local_inc, int* bsums, int n) {
    __shared__ int s[1024];
    int i = blockIdx.x * 1024 + threadIdx.x;
    int v = (i < n) ? counts[i] : 0;
    s[threadIdx.x] = v;
    __syncthreads();
    for (int off = 1; off < 1024; off <<= 1) {
        int t = 0;
        if ((int)threadIdx.x >= off) t = s[threadIdx.x - off];
        __syncthreads();
        if ((int)threadIdx.x >= off) s[threadIdx.x] += t;
        __syncthreads();
    }
    if (i < n) local_inc[i] = s[threadIdx.x];
    if (threadIdx.x == 1023) bsums[blockIdx.x] = s[1023];
}

__global__ void scan2p(int* bsums, int nb) {
    __shared__ int s[1024];
    int t = threadIdx.x;
    int v = (t < nb) ? bsums[t] : 0;
    s[t] = v;
    __syncthreads();
    for (int off = 1; off < 1024; off <<= 1) {
        int u = 0;
        if (t >= off) u = s[t - off];
        __syncthreads();
        if (t >= off) s[t] += u;
        __syncthreads();
    }
    if (t < nb) bsums[t] = s[t] - v;   // exclusive
}

__global__ void scan3(const int* local_inc, const int* counts, const int* bsums,
                      int* offsets, int n, int nE) {
    int i = blockIdx.x * blockDim.x + threadIdx.x;
    if (i < n) offsets[i] = local_inc[i] - counts[i] + bsums[i >> 10];
    if (i == 0) offsets[n] = nE;
}

__global__ void fill_csr(const int* src32, const int* dst32, const int* offsets,
                         int* cursor, int* csr_src, int nE) {
    int e = blockIdx.x * blockDim.x + threadIdx.x;
    if (e < nE) {
        int d = dst32[e];
        int pos = offsets[d] + atomicAdd(&cursor[d], 1);
        csr_src[pos] = src32[e];
    }
}

// ---------------------------------------------------------------------------
// W preprocessing: stacked [Wl;Wr] transposed to [col][k], split bf16 hi/lo.
// k<128 -> W_agg (mean half), k>=128 -> W_root (act half).
__global__ void build_wt(const float* __restrict__ Wa, const float* __restrict__ Wr,
                         __bf16* __restrict__ WtHi, __bf16* __restrict__ WtLo) {
    int idx = blockIdx.x * 256 + threadIdx.x;         // 3*128*256 total
    if (idx >= 3 * 128 * 256) return;
    int L = idx / (128 * 256);
    int rem = idx % (128 * 256);
    int c = rem / 256;
    int k = rem % 256;
    float v = (k < 128) ? Wa[((size_t)L * 128 + k) * 128 + c]
                        : Wr[((size_t)L * 128 + (k - 128)) * 128 + c];
    __bf16 h = (__bf16)v;
    __bf16 l = (__bf16)(v - (float)h);
    WtHi[idx] = h;
    WtLo[idx] = l;
}

// ---------------------------------------------------------------------------
// x fp32 -> bf16 single plane (once, layer-0 input)
__global__ void cvt_x(const float* __restrict__ x, __bf16* __restrict__ a,
                      int total8) {
    int i = blockIdx.x * 256 + threadIdx.x;           // 8 floats per thread
    if (i >= total8) return;
    const float4* p = (const float4*)(x + (size_t)i * 8);
    float4 v0 = p[0], v1 = p[1];
    float vv[8] = {v0.x, v0.y, v0.z, v0.w, v1.x, v1.y, v1.z, v1.w};
    bf16x8 h;
    #pragma unroll
    for (int j = 0; j < 8; ++j) h[j] = (__bf16)vv[j];
    *(bf16x8*)(a + (size_t)i * 8) = h;
}

// ---------------------------------------------------------------------------
// mean aggregation v5: gather bf16 plane (256B/row), one node per 16-lane
// group (bf16x8 = 16B/lane), 4x unrolled row gathers, fp32 accumulate,
// single-plane bf16 mean out.
__global__ __launch_bounds__(256) void agg_mean5(
        const __bf16* __restrict__ act, const int* __restrict__ csr,
        const int* __restrict__ offs, __bf16* __restrict__ mean, int n) {
    int node = (blockIdx.x * blockDim.x + threadIdx.x) >> 4;
    int l8 = (threadIdx.x & 15) << 3;
    if (node >= n) return;
    int beg = offs[node], end = offs[node + 1];
    float acc[8] = {0.f, 0.f, 0.f, 0.f, 0.f, 0.f, 0.f, 0.f};
    int i = beg;
    for (; i + 4 <= end; i += 4) {
        int s0 = csr[i], s1 = csr[i + 1], s2 = csr[i + 2], s3 = csr[i + 3];
        bf16x8 v0 = *(const bf16x8*)(act + (size_t)s0 * D + l8);
        bf16x8 v1 = *(const bf16x8*)(act + (size_t)s1 * D + l8);
        bf16x8 v2 = *(const bf16x8*)(act + (size_t)s2 * D + l8);
        bf16x8 v3 = *(const bf16x8*)(act + (size_t)s3 * D + l8);
        #pragma unroll
        for (int j = 0; j < 8; ++j)
            acc[j] += (float)v0[j] + (float)v1[j] + (float)v2[j] + (float)v3[j];
    }
    for (; i < end; ++i) {
        int s = csr[i];
        bf16x8 v = *(const bf16x8*)(act + (size_t)s * D + l8);
        #pragma unroll
        for (int j = 0; j < 8; ++j) acc[j] += (float)v[j];
    }
    int deg = end - beg;
    float inv = 1.0f / (float)(deg > 1 ? deg : 1);
    bf16x8 h;
    #pragma unroll
    for (int j = 0; j < 8; ++j) h[j] = (__bf16)(acc[j] * inv);
    *(bf16x8*)(mean + (size_t)node * D + l8) = h;
}

// ---------------------------------------------------------------------------
// MFMA GEMM v6: low-VGPR, no operand LDS, ping-pong buffers (no in-place
// hazard, no operand barriers). Block = 256 thr = 4 waves; block owns one
// 16-row tile x one 64-col half; wave w owns cols half*64 + w*16..+15.
// Per wave: W frags (16 cols x K=256, hi+lo) = 64 VGPR, A frags (own rows,
// single bf16 plane) = 32 VGPR -> ~130 total, 3 blocks/CU.
// acc = sum_c8 mfma(Wh, A) + mfma(Wl, A)  [operand-swapped, R4-verified:
// out_col = colbase + kg*4 + j, out_row = t*16 + r16].
// Epilogue: acc -> 4KB LDS tile -> cooperative coalesced row stores.
__global__ __launch_bounds__(256, 3) void sage_gemm6(
        const __bf16* __restrict__ mean, const __bf16* __restrict__ act,
        const __bf16* __restrict__ WtHi, const __bf16* __restrict__ WtLo,
        const float* __restrict__ bias,
        __bf16* __restrict__ oB, float* __restrict__ oF,
        int n, int mode, int ntiles) {
    __shared__ __align__(16) char sC[4096];
    int tid  = threadIdx.x;
    int wave = tid >> 6;
    int lane = tid & 63;
    int r16  = lane & 15;
    int kg   = lane >> 4;
    int half = blockIdx.x & 1;
    int colbase = half * 64 + wave * 16;

    // W fragments: this wave's 16 cols, full stacked K, hi+lo
    bf16x8 BH[8], BL[8];
    #pragma unroll
    for (int c8 = 0; c8 < 8; ++c8) {
        size_t o = (size_t)(colbase + r16) * 256 + c8 * 32 + kg * 8;
        BH[c8] = *(const bf16x8*)(WtHi + o);
        BL[c8] = *(const bf16x8*)(WtLo + o);
    }
    float4 bv = *(const float4*)(bias + colbase + kg * 4);

    bf16x8 zero;
    #pragma unroll
    for (int j = 0; j < 8; ++j) zero[j] = (__bf16)0.f;

    int t0 = blockIdx.x >> 1;
    int tstride = gridDim.x >> 1;

    for (int t = t0; t < ntiles; t += tstride) {
        int row = t * 16 + r16;
        bool valid = row < n;

        bf16x8 A[8];
        #pragma unroll
        for (int c8 = 0; c8 < 8; ++c8) {
            const __bf16* src = (c8 < 4) ? mean : act;
            size_t o = (size_t)row * D + (c8 & 3) * 32 + kg * 8;
            A[c8] = valid ? *(const bf16x8*)(src + o) : zero;
        }

        f32x4 acc = (f32x4){0.f, 0.f, 0.f, 0.f};
        #pragma unroll
        for (int c8 = 0; c8 < 8; ++c8) {
            acc = __builtin_amdgcn_mfma_f32_16x16x32_bf16(BH[c8], A[c8], acc, 0, 0, 0);
            acc = __builtin_amdgcn_mfma_f32_16x16x32_bf16(BL[c8], A[c8], acc, 0, 0, 0);
        }

        float v0 = acc[0] + bv.x;
        float v1 = acc[1] + bv.y;
        float v2 = acc[2] + bv.z;
        float v3 = acc[3] + bv.w;

        __syncthreads();   // previous tile's readback done (WAR on sC)
        if (mode == 0) {
            v0 = fmaxf(v0, 0.f); v1 = fmaxf(v1, 0.f);
            v2 = fmaxf(v2, 0.f); v3 = fmaxf(v3, 0.f);
            bf16x4 h4;
            h4[0] = (__bf16)v0; h4[1] = (__bf16)v1;
            h4[2] = (__bf16)v2; h4[3] = (__bf16)v3;
            // bf16 tile [16 rows][64 cols]: byte = r*128 + col_in_half*2
            *(bf16x4*)(sC + r16 * 128 + (wave * 16 + kg * 4) * 2) = h4;
        } else {
            *(f32x4*)(sC + r16 * 256 + (wave * 16 + kg * 4) * 4) =
                (f32x4){v0, v1, v2, v3};
        }
        __syncthreads();

        // cooperative coalesced store: full rows, contiguous per row
        int rr = tid >> 4;
        int cid = tid & 15;
        int grow = t * 16 + rr;
        if (grow < n) {
            if (mode == 0) {
                bf16x4 h4 = *(const bf16x4*)(sC + rr * 128 + cid * 8);
                *(bf16x4*)(oB + (size_t)grow * D + half * 64 + cid * 4) = h4;
            } else {
                f32x4 f4 = *(const f32x4*)(sC + rr * 256 + cid * 16);
                *(f32x4*)(oF + (size_t)grow * D + half * 64 + cid * 4) = f4;
            }
        }
    }
}

// ---------------------------------------------------------------------------
extern "C" void kernel_launch(void* const* d_in, const int* in_sizes, int n_in,
                              void* d_out, int out_size, void* d_ws, size_t ws_size,
                              hipStream_t stream) {
    const float* x  = (const float*)d_in[0];
    const void*  ei = d_in[1];
    const float* Wa = (const float*)d_in[2];   // [3,128,128]
    const float* Wr = (const float*)d_in[3];   // [3,128,128]
    const float* bb = (const float*)d_in[4];   // [3,128]
    float* outp = (float*)d_out;

    int n  = in_sizes[0] / D;          // 100000
    int nE = in_sizes[1] / 2;          // 1600000

    char* ws = (char*)d_ws;
    size_t off = 0;
    auto alloc = [&](size_t bytes) -> char* {
        char* p = ws + off;
        off = (off + bytes + 255) & ~(size_t)255;
        return p;
    };
    int* flag      = (int*)alloc(4);
    int* src32     = (int*)alloc((size_t)nE * 4);
    int* dst32     = (int*)alloc((size_t)nE * 4);
    int* counts    = (int*)alloc((size_t)n * 4);
    int* offsets   = (int*)alloc(((size_t)n + 1) * 4);
    int* cursor    = (int*)alloc((size_t)n * 4);
    int* local_inc = (int*)alloc((size_t)n * 4);
    int* bsums     = (int*)alloc(4096);
    int* csr_src   = (int*)alloc((size_t)nE * 4);
    __bf16* actA   = (__bf16*)alloc((size_t)n * D * 2);
    __bf16* actB   = (__bf16*)alloc((size_t)n * D * 2);
    __bf16* meanP  = (__bf16*)alloc((size_t)n * D * 2);
    __bf16* WtHi   = (__bf16*)alloc((size_t)3 * 128 * 256 * 2);
    __bf16* WtLo   = (__bf16*)alloc((size_t)3 * 128 * 256 * 2);
    (void)ws_size; (void)n_in; (void)out_size;

    const int B = 256;
    int ge = (nE + B - 1) / B;
    int nb = (n + 1023) / 1024;
    int gn = (n + B - 1) / B;

    // 1) index probe + conversion + W transpose/split + x convert
    hipLaunchKernelGGL(detect_idx, dim3(1), dim3(64), 0, stream, ei, flag, n);
    hipLaunchKernelGGL(convert_idx, dim3(ge), dim3(B), 0, stream,
                       ei, flag, src32, dst32, nE);
    hipLaunchKernelGGL(build_wt, dim3(384), dim3(256), 0, stream, Wa, Wr, WtHi, WtLo);
    int total8 = n * D / 8;
    hipLaunchKernelGGL(cvt_x, dim3((total8 + 255) / 256), dim3(256), 0, stream,
                       x, actA, total8);

    // 2) CSR build
    hipMemsetAsync(counts, 0, (size_t)n * 4, stream);
    hipMemsetAsync(cursor, 0, (size_t)n * 4, stream);
    hipLaunchKernelGGL(hist_kernel, dim3(ge), dim3(B), 0, stream, dst32, counts, nE);
    hipLaunchKernelGGL(scan1, dim3(nb), dim3(1024), 0, stream,
                       counts, local_inc, bsums, n);
    hipLaunchKernelGGL(scan2p, dim3(1), dim3(1024), 0, stream, bsums, nb);
    hipLaunchKernelGGL(scan3, dim3(gn), dim3(B), 0, stream,
                       local_inc, counts, bsums, offsets, n, nE);
    hipLaunchKernelGGL(fill_csr, dim3(ge), dim3(B), 0, stream,
                       src32, dst32, offsets, cursor, csr_src, nE);

    // 3) layers (ping-pong actA <-> actB; mean buffer reused)
    int agg_blocks = (n * 16 + B - 1) / B;
    int ntiles = (n + 15) / 16;
    int gemm_grid = 768;               // 3 blocks/CU, halves interleaved
    const int WSTRIDE = 128 * 256;

    // layer 0: actA -> actB (ReLU, bf16)
    hipLaunchKernelGGL(agg_mean5, dim3(agg_blocks), dim3(B), 0, stream,
                       actA, csr_src, offsets, meanP, n);
    hipLaunchKernelGGL(sage_gemm6, dim3(gemm_grid), dim3(B), 0, stream,
                       meanP, actA, WtHi + 0 * WSTRIDE, WtLo + 0 * WSTRIDE,
                       bb + 0 * D, actB, outp, n, 0, ntiles);

    // layer 1: actB -> actA (ReLU, bf16)
    hipLaunchKernelGGL(agg_mean5, dim3(agg_blocks), dim3(B), 0, stream,
                       actB, csr_src, offsets, meanP, n);
    hipLaunchKernelGGL(sage_gemm6, dim3(gemm_grid), dim3(B), 0, stream,
                       meanP, actB, WtHi + 1 * WSTRIDE, WtLo + 1 * WSTRIDE,
                       bb + 1 * D, actA, outp, n, 0, ntiles);

    // layer 2: actA -> d_out (no ReLU, fp32)
    hipLaunchKernelGGL(agg_mean5, dim3(agg_blocks), dim3(B), 0, stream,
                       actA, csr_src, offsets, meanP, n);
    hipLaunchKernelGGL(sage_gemm6, dim3(gemm_grid), dim3(B), 0, stream,
                       meanP, actA, WtHi + 2 * WSTRIDE, WtLo + 2 * WSTRIDE,
                       bb + 2 * D, actB, outp, n, 1, ntiles);
}

// Round 7
// 512.423 us; speedup vs baseline: 2.1827x; 1.0299x over previous
//
#include <hip/hip_runtime.h>
#include <stdint.h>

#define D 128

typedef __attribute__((ext_vector_type(8))) __bf16 bf16x8;
typedef __attribute__((ext_vector_type(4))) __bf16 bf16x4;
typedef __attribute__((ext_vector_type(4))) float f32x4;

// ---------------------------------------------------------------------------
// edge_index dtype detection (int64 per reference vs int32 from x64-disabled JAX)
__global__ void detect_idx(const void* ei, int* flag, int n_nodes) {
    if (blockIdx.x == 0 && threadIdx.x == 0) {
        const long long* p = (const long long*)ei;
        int is64 = 1;
        for (int i = 0; i < 64; ++i) {
            long long v = p[i];
            if (v < 0 || v >= (long long)n_nodes) { is64 = 0; break; }
        }
        *flag = is64;
    }
}

__global__ void convert_idx(const void* ei, const int* flag,
                            int* src32, int* dst32, int nE) {
    int e = blockIdx.x * blockDim.x + threadIdx.x;
    if (e >= nE) return;
    if (*flag) {
        const long long* p = (const long long*)ei;
        src32[e] = (int)p[e];
        dst32[e] = (int)p[(size_t)nE + e];
    } else {
        const int* p = (const int*)ei;
        src32[e] = p[e];
        dst32[e] = p[nE + e];
    }
}

// ---------------------------------------------------------------------------
// XCD-partitioned CSR build: group g = blockIdx&7 (round-robin XCD heuristic)
// owns dst range [n*g/8, n*(g+1)/8). Each group scans ALL edges, filters, and
// its atomics/scatter-writes stay in ONE XCD's L2 -> no cross-XCD line
// bouncing, no HBM write amplification (R6: fill_csr wrote 107MB for 6.4MB).
__global__ __launch_bounds__(256) void hist_part(
        const int* __restrict__ dst32, int* __restrict__ counts, int nE, int n) {
    int g  = blockIdx.x & 7;
    int b  = blockIdx.x >> 3;
    int nb = gridDim.x >> 3;
    int rlo = (int)(((long long)n * g) >> 3);
    int rhi = (int)(((long long)n * (g + 1)) >> 3);
    int chunk = (nE + nb - 1) / nb;
    int e0 = b * chunk;
    int e1 = min(nE, e0 + chunk);
    for (int e = e0 + (int)threadIdx.x; e < e1; e += 256) {
        int d = dst32[e];
        if (d >= rlo && d < rhi) atomicAdd(&counts[d], 1);
    }
}

__global__ __launch_bounds__(256) void fill_part(
        const int* __restrict__ src32, const int* __restrict__ dst32,
        const int* __restrict__ offsets, int* __restrict__ cursor,
        int* __restrict__ csr_src, int nE, int n) {
    int g  = blockIdx.x & 7;
    int b  = blockIdx.x >> 3;
    int nb = gridDim.x >> 3;
    int rlo = (int)(((long long)n * g) >> 3);
    int rhi = (int)(((long long)n * (g + 1)) >> 3);
    int chunk = (nE + nb - 1) / nb;
    int e0 = b * chunk;
    int e1 = min(nE, e0 + chunk);
    for (int e = e0 + (int)threadIdx.x; e < e1; e += 256) {
        int d = dst32[e];
        if (d >= rlo && d < rhi) {
            int pos = offsets[d] + atomicAdd(&cursor[d], 1);
            csr_src[pos] = src32[e];
        }
    }
}

// ---------------------------------------------------------------------------
// prefix-sum chain: counts -> offsets
__global__ void scan1(const int* counts, int* local_inc, int* bsums, int n) {
    __shared__ int s[1024];
    int i = blockIdx.x * 1024 + threadIdx.x;
    int v = (i < n) ? counts[i] : 0;
    s[threadIdx.x] = v;
    __syncthreads();
    for (int off = 1; off < 1024; off <<= 1) {
        int t = 0;
        if ((int)threadIdx.x >= off) t = s[threadIdx.x - off];
        __syncthreads();
        if ((int)threadIdx.x >= off) s[threadIdx.x] += t;
        __syncthreads();
    }
    if (i < n) local_inc[i] = s[threadIdx.x];
    if (threadIdx.x == 1023) bsums[blockIdx.x] = s[1023];
}

__global__ void scan2p(int* bsums, int nb) {
    __shared__ int s[1024];
    int t = threadIdx.x;
    int v = (t < nb) ? bsums[t] : 0;
    s[t] = v;
    __syncthreads();
    for (int off = 1; off < 1024; off <<= 1) {
        int u = 0;
        if (t >= off) u = s[t - off];
        __syncthreads();
        if (t >= off) s[t] += u;
        __syncthreads();
    }
    if (t < nb) bsums[t] = s[t] - v;   // exclusive
}

__global__ void scan3(const int* local_inc, const int* counts, const int* bsums,
                      int* offsets, int n, int nE) {
    int i = blockIdx.x * blockDim.x + threadIdx.x;
    if (i < n) offsets[i] = local_inc[i] - counts[i] + bsums[i >> 10];
    if (i == 0) offsets[n] = nE;
}

// ---------------------------------------------------------------------------
// W preprocessing: stacked [Wl;Wr] transposed to [col][k], split bf16 hi/lo.
__global__ void build_wt(const float* __restrict__ Wa, const float* __restrict__ Wr,
                         __bf16* __restrict__ WtHi, __bf16* __restrict__ WtLo) {
    int idx = blockIdx.x * 256 + threadIdx.x;         // 3*128*256 total
    if (idx >= 3 * 128 * 256) return;
    int L = idx / (128 * 256);
    int rem = idx % (128 * 256);
    int c = rem / 256;
    int k = rem % 256;
    float v = (k < 128) ? Wa[((size_t)L * 128 + k) * 128 + c]
                        : Wr[((size_t)L * 128 + (k - 128)) * 128 + c];
    __bf16 h = (__bf16)v;
    __bf16 l = (__bf16)(v - (float)h);
    WtHi[idx] = h;
    WtLo[idx] = l;
}

// ---------------------------------------------------------------------------
// x fp32 -> bf16 single plane (once, layer-0 input)
__global__ void cvt_x(const float* __restrict__ x, __bf16* __restrict__ a,
                      int total8) {
    int i = blockIdx.x * 256 + threadIdx.x;           // 8 floats per thread
    if (i >= total8) return;
    const float4* p = (const float4*)(x + (size_t)i * 8);
    float4 v0 = p[0], v1 = p[1];
    float vv[8] = {v0.x, v0.y, v0.z, v0.w, v1.x, v1.y, v1.z, v1.w};
    bf16x8 h;
    #pragma unroll
    for (int j = 0; j < 8; ++j) h[j] = (__bf16)vv[j];
    *(bf16x8*)(a + (size_t)i * 8) = h;
}

// ---------------------------------------------------------------------------
// mean aggregation: gather bf16 plane (256B/row), one node per 16-lane group
// (bf16x8 = 16B/lane), 8x then 4x unrolled row gathers, fp32 accumulate.
__global__ __launch_bounds__(256) void agg_mean5(
        const __bf16* __restrict__ act, const int* __restrict__ csr,
        const int* __restrict__ offs, __bf16* __restrict__ mean, int n) {
    int node = (blockIdx.x * blockDim.x + threadIdx.x) >> 4;
    int l8 = (threadIdx.x & 15) << 3;
    if (node >= n) return;
    int beg = offs[node], end = offs[node + 1];
    float acc[8] = {0.f, 0.f, 0.f, 0.f, 0.f, 0.f, 0.f, 0.f};
    int i = beg;
    for (; i + 8 <= end; i += 8) {
        bf16x8 v[8];
        #pragma unroll
        for (int u = 0; u < 8; ++u)
            v[u] = *(const bf16x8*)(act + (size_t)csr[i + u] * D + l8);
        #pragma unroll
        for (int u = 0; u < 8; ++u)
            #pragma unroll
            for (int j = 0; j < 8; ++j) acc[j] += (float)v[u][j];
    }
    for (; i + 4 <= end; i += 4) {
        bf16x8 v[4];
        #pragma unroll
        for (int u = 0; u < 4; ++u)
            v[u] = *(const bf16x8*)(act + (size_t)csr[i + u] * D + l8);
        #pragma unroll
        for (int u = 0; u < 4; ++u)
            #pragma unroll
            for (int j = 0; j < 8; ++j) acc[j] += (float)v[u][j];
    }
    for (; i < end; ++i) {
        bf16x8 v = *(const bf16x8*)(act + (size_t)csr[i] * D + l8);
        #pragma unroll
        for (int j = 0; j < 8; ++j) acc[j] += (float)v[j];
    }
    int deg = end - beg;
    float inv = 1.0f / (float)(deg > 1 ? deg : 1);
    bf16x8 h;
    #pragma unroll
    for (int j = 0; j < 8; ++j) h[j] = (__bf16)(acc[j] * inv);
    *(bf16x8*)(mean + (size_t)node * D + l8) = h;
}

// ---------------------------------------------------------------------------
// MFMA GEMM v6 (unchanged from R6): low-VGPR, ping-pong buffers, W frags in
// registers, operand-swapped mfma (out_row = t*16+r16, out_col = colbase+kg*4+j),
// coalesced epilogue via 4KB LDS tile.
__global__ __launch_bounds__(256, 3) void sage_gemm6(
        const __bf16* __restrict__ mean, const __bf16* __restrict__ act,
        const __bf16* __restrict__ WtHi, const __bf16* __restrict__ WtLo,
        const float* __restrict__ bias,
        __bf16* __restrict__ oB, float* __restrict__ oF,
        int n, int mode, int ntiles) {
    __shared__ __align__(16) char sC[4096];
    int tid  = threadIdx.x;
    int wave = tid >> 6;
    int lane = tid & 63;
    int r16  = lane & 15;
    int kg   = lane >> 4;
    int half = blockIdx.x & 1;
    int colbase = half * 64 + wave * 16;

    bf16x8 BH[8], BL[8];
    #pragma unroll
    for (int c8 = 0; c8 < 8; ++c8) {
        size_t o = (size_t)(colbase + r16) * 256 + c8 * 32 + kg * 8;
        BH[c8] = *(const bf16x8*)(WtHi + o);
        BL[c8] = *(const bf16x8*)(WtLo + o);
    }
    float4 bv = *(const float4*)(bias + colbase + kg * 4);

    bf16x8 zero;
    #pragma unroll
    for (int j = 0; j < 8; ++j) zero[j] = (__bf16)0.f;

    int t0 = blockIdx.x >> 1;
    int tstride = gridDim.x >> 1;

    for (int t = t0; t < ntiles; t += tstride) {
        int row = t * 16 + r16;
        bool valid = row < n;

        bf16x8 A[8];
        #pragma unroll
        for (int c8 = 0; c8 < 8; ++c8) {
            const __bf16* src = (c8 < 4) ? mean : act;
            size_t o = (size_t)row * D + (c8 & 3) * 32 + kg * 8;
            A[c8] = valid ? *(const bf16x8*)(src + o) : zero;
        }

        f32x4 acc = (f32x4){0.f, 0.f, 0.f, 0.f};
        #pragma unroll
        for (int c8 = 0; c8 < 8; ++c8) {
            acc = __builtin_amdgcn_mfma_f32_16x16x32_bf16(BH[c8], A[c8], acc, 0, 0, 0);
            acc = __builtin_amdgcn_mfma_f32_16x16x32_bf16(BL[c8], A[c8], acc, 0, 0, 0);
        }

        float v0 = acc[0] + bv.x;
        float v1 = acc[1] + bv.y;
        float v2 = acc[2] + bv.z;
        float v3 = acc[3] + bv.w;

        __syncthreads();   // previous tile's readback done (WAR on sC)
        if (mode == 0) {
            v0 = fmaxf(v0, 0.f); v1 = fmaxf(v1, 0.f);
            v2 = fmaxf(v2, 0.f); v3 = fmaxf(v3, 0.f);
            bf16x4 h4;
            h4[0] = (__bf16)v0; h4[1] = (__bf16)v1;
            h4[2] = (__bf16)v2; h4[3] = (__bf16)v3;
            *(bf16x4*)(sC + r16 * 128 + (wave * 16 + kg * 4) * 2) = h4;
        } else {
            *(f32x4*)(sC + r16 * 256 + (wave * 16 + kg * 4) * 4) =
                (f32x4){v0, v1, v2, v3};
        }
        __syncthreads();

        int rr = tid >> 4;
        int cid = tid & 15;
        int grow = t * 16 + rr;
        if (grow < n) {
            if (mode == 0) {
                bf16x4 h4 = *(const bf16x4*)(sC + rr * 128 + cid * 8);
                *(bf16x4*)(oB + (size_t)grow * D + half * 64 + cid * 4) = h4;
            } else {
                f32x4 f4 = *(const f32x4*)(sC + rr * 256 + cid * 16);
                *(f32x4*)(oF + (size_t)grow * D + half * 64 + cid * 4) = f4;
            }
        }
    }
}

// ---------------------------------------------------------------------------
extern "C" void kernel_launch(void* const* d_in, const int* in_sizes, int n_in,
                              void* d_out, int out_size, void* d_ws, size_t ws_size,
                              hipStream_t stream) {
    const float* x  = (const float*)d_in[0];
    const void*  ei = d_in[1];
    const float* Wa = (const float*)d_in[2];   // [3,128,128]
    const float* Wr = (const float*)d_in[3];   // [3,128,128]
    const float* bb = (const float*)d_in[4];   // [3,128]
    float* outp = (float*)d_out;

    int n  = in_sizes[0] / D;          // 100000
    int nE = in_sizes[1] / 2;          // 1600000

    char* ws = (char*)d_ws;
    size_t off = 0;
    auto alloc = [&](size_t bytes) -> char* {
        char* p = ws + off;
        off = (off + bytes + 255) & ~(size_t)255;
        return p;
    };
    int* flag      = (int*)alloc(4);
    int* src32     = (int*)alloc((size_t)nE * 4);
    int* dst32     = (int*)alloc((size_t)nE * 4);
    int* counts    = (int*)alloc((size_t)n * 4);
    int* offsets   = (int*)alloc(((size_t)n + 1) * 4);
    int* cursor    = (int*)alloc((size_t)n * 4);
    int* local_inc = (int*)alloc((size_t)n * 4);
    int* bsums     = (int*)alloc(4096);
    int* csr_src   = (int*)alloc((size_t)nE * 4);
    __bf16* actA   = (__bf16*)alloc((size_t)n * D * 2);
    __bf16* actB   = (__bf16*)alloc((size_t)n * D * 2);
    __bf16* meanP  = (__bf16*)alloc((size_t)n * D * 2);
    __bf16* WtHi   = (__bf16*)alloc((size_t)3 * 128 * 256 * 2);
    __bf16* WtLo   = (__bf16*)alloc((size_t)3 * 128 * 256 * 2);
    (void)ws_size; (void)n_in; (void)out_size;

    const int B = 256;
    int ge = (nE + B - 1) / B;
    int nb = (n + 1023) / 1024;
    int gn = (n + B - 1) / B;

    // 1) index probe + conversion + W transpose/split + x convert
    hipLaunchKernelGGL(detect_idx, dim3(1), dim3(64), 0, stream, ei, flag, n);
    hipLaunchKernelGGL(convert_idx, dim3(ge), dim3(B), 0, stream,
                       ei, flag, src32, dst32, nE);
    hipLaunchKernelGGL(build_wt, dim3(384), dim3(256), 0, stream, Wa, Wr, WtHi, WtLo);
    int total8 = n * D / 8;
    hipLaunchKernelGGL(cvt_x, dim3((total8 + 255) / 256), dim3(256), 0, stream,
                       x, actA, total8);

    // 2) CSR build (XCD-partitioned hist + fill)
    hipMemsetAsync(counts, 0, (size_t)n * 4, stream);
    hipMemsetAsync(cursor, 0, (size_t)n * 4, stream);
    hipLaunchKernelGGL(hist_part, dim3(1024), dim3(B), 0, stream, dst32, counts, nE, n);
    hipLaunchKernelGGL(scan1, dim3(nb), dim3(1024), 0, stream,
                       counts, local_inc, bsums, n);
    hipLaunchKernelGGL(scan2p, dim3(1), dim3(1024), 0, stream, bsums, nb);
    hipLaunchKernelGGL(scan3, dim3(gn), dim3(B), 0, stream,
                       local_inc, counts, bsums, offsets, n, nE);
    hipLaunchKernelGGL(fill_part, dim3(1024), dim3(B), 0, stream,
                       src32, dst32, offsets, cursor, csr_src, nE, n);

    // 3) layers (ping-pong actA <-> actB; mean buffer reused)
    int agg_blocks = (n * 16 + B - 1) / B;
    int ntiles = (n + 15) / 16;
    int gemm_grid = 768;               // 3 blocks/CU, halves interleaved
    const int WSTRIDE = 128 * 256;

    // layer 0: actA -> actB (ReLU, bf16)
    hipLaunchKernelGGL(agg_mean5, dim3(agg_blocks), dim3(B), 0, stream,
                       actA, csr_src, offsets, meanP, n);
    hipLaunchKernelGGL(sage_gemm6, dim3(gemm_grid), dim3(B), 0, stream,
                       meanP, actA, WtHi + 0 * WSTRIDE, WtLo + 0 * WSTRIDE,
                       bb + 0 * D, actB, outp, n, 0, ntiles);

    // layer 1: actB -> actA (ReLU, bf16)
    hipLaunchKernelGGL(agg_mean5, dim3(agg_blocks), dim3(B), 0, stream,
                       actB, csr_src, offsets, meanP, n);
    hipLaunchKernelGGL(sage_gemm6, dim3(gemm_grid), dim3(B), 0, stream,
                       meanP, actB, WtHi + 1 * WSTRIDE, WtLo + 1 * WSTRIDE,
                       bb + 1 * D, actA, outp, n, 0, ntiles);

    // layer 2: actA -> d_out (no ReLU, fp32)
    hipLaunchKernelGGL(agg_mean5, dim3(agg_blocks), dim3(B), 0, stream,
                       actA, csr_src, offsets, meanP, n);
    hipLaunchKernelGGL(sage_gemm6, dim3(gemm_grid), dim3(B), 0, stream,
                       meanP, actA, WtHi + 2 * WSTRIDE, WtLo + 2 * WSTRIDE,
                       bb + 2 * D, actB, outp, n, 1, ntiles);
}

// Round 8
// 431.627 us; speedup vs baseline: 2.5913x; 1.1872x over previous
//
#include <hip/hip_runtime.h>
#include <stdint.h>

#define D 128
#define CHUNK 3200

typedef __attribute__((ext_vector_type(8))) __bf16 bf16x8;
typedef __attribute__((ext_vector_type(4))) __bf16 bf16x4;
typedef __attribute__((ext_vector_type(4))) float f32x4;

// ---------------------------------------------------------------------------
// edge_index dtype detection (int64 per reference vs int32 from x64-disabled JAX)
__global__ void detect_idx(const void* ei, int* flag, int n_nodes) {
    if (blockIdx.x == 0 && threadIdx.x == 0) {
        const long long* p = (const long long*)ei;
        int is64 = 1;
        for (int i = 0; i < 64; ++i) {
            long long v = p[i];
            if (v < 0 || v >= (long long)n_nodes) { is64 = 0; break; }
        }
        *flag = is64;
    }
}

__global__ void convert_idx(const void* ei, const int* flag,
                            int* src32, int* dst32, int nE) {
    int e = blockIdx.x * blockDim.x + threadIdx.x;
    if (e >= nE) return;
    if (*flag) {
        const long long* p = (const long long*)ei;
        src32[e] = (int)p[e];
        dst32[e] = (int)p[(size_t)nE + e];
    } else {
        const int* p = (const int*)ei;
        src32[e] = p[e];
        dst32[e] = p[nE + e];
    }
}

// ---------------------------------------------------------------------------
// Bucketed CSR build. Bucket g = dst>>9 (512 nodes per bucket, G<=256).
// The final scatter for each bucket is done by ONE workgroup -> all its
// partially-written cache lines live in a single XCD's L2 and write back
// once (R6/R7 lesson: cross-XCD scatter caused 12-16x HBM write amp).

// per-block LDS bucket histogram, flushed with <=256 global atomics
__global__ __launch_bounds__(256) void bucket_hist(
        const int* __restrict__ dst32, int* __restrict__ bcnt, int nE) {
    __shared__ int l[256];
    l[threadIdx.x] = 0;
    __syncthreads();
    int stride = gridDim.x * 256;
    for (int e = blockIdx.x * 256 + threadIdx.x; e < nE; e += stride)
        atomicAdd(&l[dst32[e] >> 9], 1);
    __syncthreads();
    int v = l[threadIdx.x];
    if (v) atomicAdd(&bcnt[threadIdx.x], v);
}

// exclusive scan of bucket counts -> bstart, bcur; also offsets[n]=nE
__global__ void bucket_scan(const int* __restrict__ bcnt, int* __restrict__ bstart,
                            int* __restrict__ bcur, int G, int nE,
                            int* __restrict__ offsets, int n) {
    __shared__ int s[256];
    int t = threadIdx.x;
    int v = (t < G) ? bcnt[t] : 0;
    s[t] = v;
    __syncthreads();
    for (int off = 1; off < 256; off <<= 1) {
        int u = 0;
        if (t >= off) u = s[t - off];
        __syncthreads();
        if (t >= off) s[t] += u;
        __syncthreads();
    }
    if (t < G) { int ex = s[t] - v; bstart[t] = ex; bcur[t] = ex; }
    if (t == 0) offsets[n] = nE;
}

// pass 1: chunk -> LDS, count per bucket, reserve space, write bucket-major
// (src,dst) pairs. Per-(block,bucket) output runs are contiguous.
__global__ __launch_bounds__(256) void bucket_fill(
        const int* __restrict__ src32, const int* __restrict__ dst32,
        int* __restrict__ bcur, int* __restrict__ ebs, int* __restrict__ ebd,
        int nE) {
    __shared__ int ls[CHUNK], ld_[CHUNK];
    __shared__ int lcnt[256], lbase[256], lcur[256];
    int e0 = blockIdx.x * CHUNK;
    int cnt = nE - e0;
    if (cnt > CHUNK) cnt = CHUNK;
    if (cnt < 0) cnt = 0;
    for (int i = threadIdx.x; i < cnt; i += 256) {
        ls[i]  = src32[e0 + i];
        ld_[i] = dst32[e0 + i];
    }
    lcnt[threadIdx.x] = 0;
    __syncthreads();
    for (int i = threadIdx.x; i < cnt; i += 256)
        atomicAdd(&lcnt[ld_[i] >> 9], 1);
    __syncthreads();
    int c = lcnt[threadIdx.x];
    if (c > 0) lbase[threadIdx.x] = atomicAdd(&bcur[threadIdx.x], c);
    lcur[threadIdx.x] = 0;
    __syncthreads();
    for (int i = threadIdx.x; i < cnt; i += 256) {
        int g = ld_[i] >> 9;
        int p = lbase[g] + atomicAdd(&lcur[g], 1);
        ebs[p] = ls[i];
        ebd[p] = ld_[i];
    }
}

// pass 2: one block per bucket. Node-histogram its 512-node range, scan,
// write offsets slice (coalesced), scatter csr within its own dense window.
__global__ __launch_bounds__(256) void bucket_scatter(
        const int* __restrict__ ebs, const int* __restrict__ ebd,
        const int* __restrict__ bstart, const int* __restrict__ bcnt,
        int* __restrict__ offsets, int* __restrict__ csr, int n) {
    __shared__ int ncnt[512], nofs[512], ps[256];
    int g = blockIdx.x;
    int base = bstart[g];
    int cnt = bcnt[g];
    int n0 = g << 9;
    int nr = n - n0; if (nr > 512) nr = 512;
    for (int i = threadIdx.x; i < 512; i += 256) ncnt[i] = 0;
    __syncthreads();
    for (int i = threadIdx.x; i < cnt; i += 256)
        atomicAdd(&ncnt[ebd[base + i] - n0], 1);
    __syncthreads();
    int t = threadIdx.x;
    int c0 = ncnt[2 * t], c1 = ncnt[2 * t + 1];
    ps[t] = c0 + c1;
    __syncthreads();
    for (int off = 1; off < 256; off <<= 1) {
        int u = 0;
        if (t >= off) u = ps[t - off];
        __syncthreads();
        if (t >= off) ps[t] += u;
        __syncthreads();
    }
    int pex = ps[t] - (c0 + c1);
    nofs[2 * t] = pex;
    nofs[2 * t + 1] = pex + c0;
    __syncthreads();
    for (int i = threadIdx.x; i < nr; i += 256)
        offsets[n0 + i] = base + nofs[i];
    for (int i = threadIdx.x; i < 512; i += 256) ncnt[i] = 0;   // reuse as cursor
    __syncthreads();
    for (int i = threadIdx.x; i < cnt; i += 256) {
        int d = ebd[base + i] - n0;
        int p = base + nofs[d] + atomicAdd(&ncnt[d], 1);
        csr[p] = ebs[base + i];
    }
}

// ---------------------------------------------------------------------------
// W preprocessing: stacked [Wl;Wr] transposed to [col][k], split bf16 hi/lo.
__global__ void build_wt(const float* __restrict__ Wa, const float* __restrict__ Wr,
                         __bf16* __restrict__ WtHi, __bf16* __restrict__ WtLo) {
    int idx = blockIdx.x * 256 + threadIdx.x;         // 3*128*256 total
    if (idx >= 3 * 128 * 256) return;
    int L = idx / (128 * 256);
    int rem = idx % (128 * 256);
    int c = rem / 256;
    int k = rem % 256;
    float v = (k < 128) ? Wa[((size_t)L * 128 + k) * 128 + c]
                        : Wr[((size_t)L * 128 + (k - 128)) * 128 + c];
    __bf16 h = (__bf16)v;
    __bf16 l = (__bf16)(v - (float)h);
    WtHi[idx] = h;
    WtLo[idx] = l;
}

// ---------------------------------------------------------------------------
// x fp32 -> bf16 single plane (once, layer-0 input)
__global__ void cvt_x(const float* __restrict__ x, __bf16* __restrict__ a,
                      int total8) {
    int i = blockIdx.x * 256 + threadIdx.x;           // 8 floats per thread
    if (i >= total8) return;
    const float4* p = (const float4*)(x + (size_t)i * 8);
    float4 v0 = p[0], v1 = p[1];
    float vv[8] = {v0.x, v0.y, v0.z, v0.w, v1.x, v1.y, v1.z, v1.w};
    bf16x8 h;
    #pragma unroll
    for (int j = 0; j < 8; ++j) h[j] = (__bf16)vv[j];
    *(bf16x8*)(a + (size_t)i * 8) = h;
}

// ---------------------------------------------------------------------------
// mean aggregation: gather bf16 plane (256B/row), one node per 16-lane group
// (bf16x8 = 16B/lane), 8x then 4x unrolled row gathers, fp32 accumulate.
__global__ __launch_bounds__(256) void agg_mean5(
        const __bf16* __restrict__ act, const int* __restrict__ csr,
        const int* __restrict__ offs, __bf16* __restrict__ mean, int n) {
    int node = (blockIdx.x * blockDim.x + threadIdx.x) >> 4;
    int l8 = (threadIdx.x & 15) << 3;
    if (node >= n) return;
    int beg = offs[node], end = offs[node + 1];
    float acc[8] = {0.f, 0.f, 0.f, 0.f, 0.f, 0.f, 0.f, 0.f};
    int i = beg;
    for (; i + 8 <= end; i += 8) {
        bf16x8 v[8];
        #pragma unroll
        for (int u = 0; u < 8; ++u)
            v[u] = *(const bf16x8*)(act + (size_t)csr[i + u] * D + l8);
        #pragma unroll
        for (int u = 0; u < 8; ++u)
            #pragma unroll
            for (int j = 0; j < 8; ++j) acc[j] += (float)v[u][j];
    }
    for (; i + 4 <= end; i += 4) {
        bf16x8 v[4];
        #pragma unroll
        for (int u = 0; u < 4; ++u)
            v[u] = *(const bf16x8*)(act + (size_t)csr[i + u] * D + l8);
        #pragma unroll
        for (int u = 0; u < 4; ++u)
            #pragma unroll
            for (int j = 0; j < 8; ++j) acc[j] += (float)v[u][j];
    }
    for (; i < end; ++i) {
        bf16x8 v = *(const bf16x8*)(act + (size_t)csr[i] * D + l8);
        #pragma unroll
        for (int j = 0; j < 8; ++j) acc[j] += (float)v[j];
    }
    int deg = end - beg;
    float inv = 1.0f / (float)(deg > 1 ? deg : 1);
    bf16x8 h;
    #pragma unroll
    for (int j = 0; j < 8; ++j) h[j] = (__bf16)(acc[j] * inv);
    *(bf16x8*)(mean + (size_t)node * D + l8) = h;
}

// ---------------------------------------------------------------------------
// MFMA GEMM v6 (unchanged): low-VGPR, ping-pong buffers, W frags in registers,
// operand-swapped mfma (out_row = t*16+r16, out_col = colbase+kg*4+j),
// coalesced epilogue via 4KB LDS tile.
__global__ __launch_bounds__(256, 3) void sage_gemm6(
        const __bf16* __restrict__ mean, const __bf16* __restrict__ act,
        const __bf16* __restrict__ WtHi, const __bf16* __restrict__ WtLo,
        const float* __restrict__ bias,
        __bf16* __restrict__ oB, float* __restrict__ oF,
        int n, int mode, int ntiles) {
    __shared__ __align__(16) char sC[4096];
    int tid  = threadIdx.x;
    int wave = tid >> 6;
    int lane = tid & 63;
    int r16  = lane & 15;
    int kg   = lane >> 4;
    int half = blockIdx.x & 1;
    int colbase = half * 64 + wave * 16;

    bf16x8 BH[8], BL[8];
    #pragma unroll
    for (int c8 = 0; c8 < 8; ++c8) {
        size_t o = (size_t)(colbase + r16) * 256 + c8 * 32 + kg * 8;
        BH[c8] = *(const bf16x8*)(WtHi + o);
        BL[c8] = *(const bf16x8*)(WtLo + o);
    }
    float4 bv = *(const float4*)(bias + colbase + kg * 4);

    bf16x8 zero;
    #pragma unroll
    for (int j = 0; j < 8; ++j) zero[j] = (__bf16)0.f;

    int t0 = blockIdx.x >> 1;
    int tstride = gridDim.x >> 1;

    for (int t = t0; t < ntiles; t += tstride) {
        int row = t * 16 + r16;
        bool valid = row < n;

        bf16x8 A[8];
        #pragma unroll
        for (int c8 = 0; c8 < 8; ++c8) {
            const __bf16* src = (c8 < 4) ? mean : act;
            size_t o = (size_t)row * D + (c8 & 3) * 32 + kg * 8;
            A[c8] = valid ? *(const bf16x8*)(src + o) : zero;
        }

        f32x4 acc = (f32x4){0.f, 0.f, 0.f, 0.f};
        #pragma unroll
        for (int c8 = 0; c8 < 8; ++c8) {
            acc = __builtin_amdgcn_mfma_f32_16x16x32_bf16(BH[c8], A[c8], acc, 0, 0, 0);
            acc = __builtin_amdgcn_mfma_f32_16x16x32_bf16(BL[c8], A[c8], acc, 0, 0, 0);
        }

        float v0 = acc[0] + bv.x;
        float v1 = acc[1] + bv.y;
        float v2 = acc[2] + bv.z;
        float v3 = acc[3] + bv.w;

        __syncthreads();   // previous tile's readback done (WAR on sC)
        if (mode == 0) {
            v0 = fmaxf(v0, 0.f); v1 = fmaxf(v1, 0.f);
            v2 = fmaxf(v2, 0.f); v3 = fmaxf(v3, 0.f);
            bf16x4 h4;
            h4[0] = (__bf16)v0; h4[1] = (__bf16)v1;
            h4[2] = (__bf16)v2; h4[3] = (__bf16)v3;
            *(bf16x4*)(sC + r16 * 128 + (wave * 16 + kg * 4) * 2) = h4;
        } else {
            *(f32x4*)(sC + r16 * 256 + (wave * 16 + kg * 4) * 4) =
                (f32x4){v0, v1, v2, v3};
        }
        __syncthreads();

        int rr = tid >> 4;
        int cid = tid & 15;
        int grow = t * 16 + rr;
        if (grow < n) {
            if (mode == 0) {
                bf16x4 h4 = *(const bf16x4*)(sC + rr * 128 + cid * 8);
                *(bf16x4*)(oB + (size_t)grow * D + half * 64 + cid * 4) = h4;
            } else {
                f32x4 f4 = *(const f32x4*)(sC + rr * 256 + cid * 16);
                *(f32x4*)(oF + (size_t)grow * D + half * 64 + cid * 4) = f4;
            }
        }
    }
}

// ---------------------------------------------------------------------------
extern "C" void kernel_launch(void* const* d_in, const int* in_sizes, int n_in,
                              void* d_out, int out_size, void* d_ws, size_t ws_size,
                              hipStream_t stream) {
    const float* x  = (const float*)d_in[0];
    const void*  ei = d_in[1];
    const float* Wa = (const float*)d_in[2];   // [3,128,128]
    const float* Wr = (const float*)d_in[3];   // [3,128,128]
    const float* bb = (const float*)d_in[4];   // [3,128]
    float* outp = (float*)d_out;

    int n  = in_sizes[0] / D;          // 100000
    int nE = in_sizes[1] / 2;          // 1600000
    int G  = (n + 511) >> 9;           // 512-node buckets (G<=256 for n<=131072)

    char* ws = (char*)d_ws;
    size_t off = 0;
    auto alloc = [&](size_t bytes) -> char* {
        char* p = ws + off;
        off = (off + bytes + 255) & ~(size_t)255;
        return p;
    };
    int* flag      = (int*)alloc(4);
    int* src32     = (int*)alloc((size_t)nE * 4);
    int* dst32     = (int*)alloc((size_t)nE * 4);
    int* offsets   = (int*)alloc(((size_t)n + 1) * 4);
    int* csr_src   = (int*)alloc((size_t)nE * 4);
    int* ebs       = (int*)alloc((size_t)nE * 4);
    int* ebd       = (int*)alloc((size_t)nE * 4);
    int* bcnt      = (int*)alloc(1024);
    int* bstart    = (int*)alloc(1024);
    int* bcur      = (int*)alloc(1024);
    __bf16* actA   = (__bf16*)alloc((size_t)n * D * 2);
    __bf16* actB   = (__bf16*)alloc((size_t)n * D * 2);
    __bf16* meanP  = (__bf16*)alloc((size_t)n * D * 2);
    __bf16* WtHi   = (__bf16*)alloc((size_t)3 * 128 * 256 * 2);
    __bf16* WtLo   = (__bf16*)alloc((size_t)3 * 128 * 256 * 2);
    (void)ws_size; (void)n_in; (void)out_size;

    const int B = 256;
    int ge = (nE + B - 1) / B;

    // 1) index probe + conversion + W transpose/split + x convert
    hipLaunchKernelGGL(detect_idx, dim3(1), dim3(64), 0, stream, ei, flag, n);
    hipLaunchKernelGGL(convert_idx, dim3(ge), dim3(B), 0, stream,
                       ei, flag, src32, dst32, nE);
    hipLaunchKernelGGL(build_wt, dim3(384), dim3(256), 0, stream, Wa, Wr, WtHi, WtLo);
    int total8 = n * D / 8;
    hipLaunchKernelGGL(cvt_x, dim3((total8 + 255) / 256), dim3(256), 0, stream,
                       x, actA, total8);

    // 2) bucketed CSR build (single-XCD scatter windows)
    hipMemsetAsync(bcnt, 0, 1024, stream);
    hipLaunchKernelGGL(bucket_hist, dim3(512), dim3(B), 0, stream, dst32, bcnt, nE);
    hipLaunchKernelGGL(bucket_scan, dim3(1), dim3(B), 0, stream,
                       bcnt, bstart, bcur, G, nE, offsets, n);
    hipLaunchKernelGGL(bucket_fill, dim3((nE + CHUNK - 1) / CHUNK), dim3(B), 0, stream,
                       src32, dst32, bcur, ebs, ebd, nE);
    hipLaunchKernelGGL(bucket_scatter, dim3(G), dim3(B), 0, stream,
                       ebs, ebd, bstart, bcnt, offsets, csr_src, n);

    // 3) layers (ping-pong actA <-> actB; mean buffer reused)
    int agg_blocks = (n * 16 + B - 1) / B;
    int ntiles = (n + 15) / 16;
    int gemm_grid = 768;               // 3 blocks/CU, halves interleaved
    const int WSTRIDE = 128 * 256;

    // layer 0: actA -> actB (ReLU, bf16)
    hipLaunchKernelGGL(agg_mean5, dim3(agg_blocks), dim3(B), 0, stream,
                       actA, csr_src, offsets, meanP, n);
    hipLaunchKernelGGL(sage_gemm6, dim3(gemm_grid), dim3(B), 0, stream,
                       meanP, actA, WtHi + 0 * WSTRIDE, WtLo + 0 * WSTRIDE,
                       bb + 0 * D, actB, outp, n, 0, ntiles);

    // layer 1: actB -> actA (ReLU, bf16)
    hipLaunchKernelGGL(agg_mean5, dim3(agg_blocks), dim3(B), 0, stream,
                       actB, csr_src, offsets, meanP, n);
    hipLaunchKernelGGL(sage_gemm6, dim3(gemm_grid), dim3(B), 0, stream,
                       meanP, actB, WtHi + 1 * WSTRIDE, WtLo + 1 * WSTRIDE,
                       bb + 1 * D, actA, outp, n, 0, ntiles);

    // layer 2: actA -> d_out (no ReLU, fp32)
    hipLaunchKernelGGL(agg_mean5, dim3(agg_blocks), dim3(B), 0, stream,
                       actA, csr_src, offsets, meanP, n);
    hipLaunchKernelGGL(sage_gemm6, dim3(gemm_grid), dim3(B), 0, stream,
                       meanP, actA, WtHi + 2 * WSTRIDE, WtLo + 2 * WSTRIDE,
                       bb + 2 * D, actB, outp, n, 1, ntiles);
}

// Round 9
// 349.400 us; speedup vs baseline: 3.2011x; 1.2353x over previous
//
#include <hip/hip_runtime.h>
#include <stdint.h>

#define D 128
#define CHUNK 3200

typedef __attribute__((ext_vector_type(8))) __bf16 bf16x8;
typedef __attribute__((ext_vector_type(4))) __bf16 bf16x4;
typedef __attribute__((ext_vector_type(4))) float f32x4;

// ---------------------------------------------------------------------------
// edge_index dtype detection (int64 per reference vs int32 from x64-disabled JAX)
__global__ void detect_idx(const void* ei, int* flag, int n_nodes) {
    if (blockIdx.x == 0 && threadIdx.x == 0) {
        const long long* p = (const long long*)ei;
        int is64 = 1;
        for (int i = 0; i < 64; ++i) {
            long long v = p[i];
            if (v < 0 || v >= (long long)n_nodes) { is64 = 0; break; }
        }
        *flag = is64;
    }
}

__global__ void convert_idx(const void* ei, const int* flag,
                            int* src32, int* dst32, int nE) {
    int e = blockIdx.x * blockDim.x + threadIdx.x;
    if (e >= nE) return;
    if (*flag) {
        const long long* p = (const long long*)ei;
        src32[e] = (int)p[e];
        dst32[e] = (int)p[(size_t)nE + e];
    } else {
        const int* p = (const int*)ei;
        src32[e] = p[e];
        dst32[e] = p[nE + e];
    }
}

// ---------------------------------------------------------------------------
// Bucketed CSR build (R8-verified). Bucket g = dst>>9; final scatter per
// bucket done by ONE workgroup -> no cross-XCD line bouncing / write amp.
__global__ __launch_bounds__(256) void bucket_hist(
        const int* __restrict__ dst32, int* __restrict__ bcnt, int nE) {
    __shared__ int l[256];
    l[threadIdx.x] = 0;
    __syncthreads();
    int stride = gridDim.x * 256;
    for (int e = blockIdx.x * 256 + threadIdx.x; e < nE; e += stride)
        atomicAdd(&l[dst32[e] >> 9], 1);
    __syncthreads();
    int v = l[threadIdx.x];
    if (v) atomicAdd(&bcnt[threadIdx.x], v);
}

__global__ void bucket_scan(const int* __restrict__ bcnt, int* __restrict__ bstart,
                            int* __restrict__ bcur, int G, int nE,
                            int* __restrict__ offsets, int n) {
    __shared__ int s[256];
    int t = threadIdx.x;
    int v = (t < G) ? bcnt[t] : 0;
    s[t] = v;
    __syncthreads();
    for (int off = 1; off < 256; off <<= 1) {
        int u = 0;
        if (t >= off) u = s[t - off];
        __syncthreads();
        if (t >= off) s[t] += u;
        __syncthreads();
    }
    if (t < G) { int ex = s[t] - v; bstart[t] = ex; bcur[t] = ex; }
    if (t == 0) offsets[n] = nE;
}

__global__ __launch_bounds__(256) void bucket_fill(
        const int* __restrict__ src32, const int* __restrict__ dst32,
        int* __restrict__ bcur, int* __restrict__ ebs, int* __restrict__ ebd,
        int nE) {
    __shared__ int ls[CHUNK], ld_[CHUNK];
    __shared__ int lcnt[256], lbase[256], lcur[256];
    int e0 = blockIdx.x * CHUNK;
    int cnt = nE - e0;
    if (cnt > CHUNK) cnt = CHUNK;
    if (cnt < 0) cnt = 0;
    for (int i = threadIdx.x; i < cnt; i += 256) {
        ls[i]  = src32[e0 + i];
        ld_[i] = dst32[e0 + i];
    }
    lcnt[threadIdx.x] = 0;
    __syncthreads();
    for (int i = threadIdx.x; i < cnt; i += 256)
        atomicAdd(&lcnt[ld_[i] >> 9], 1);
    __syncthreads();
    int c = lcnt[threadIdx.x];
    if (c > 0) lbase[threadIdx.x] = atomicAdd(&bcur[threadIdx.x], c);
    lcur[threadIdx.x] = 0;
    __syncthreads();
    for (int i = threadIdx.x; i < cnt; i += 256) {
        int g = ld_[i] >> 9;
        int p = lbase[g] + atomicAdd(&lcur[g], 1);
        ebs[p] = ls[i];
        ebd[p] = ld_[i];
    }
}

__global__ __launch_bounds__(256) void bucket_scatter(
        const int* __restrict__ ebs, const int* __restrict__ ebd,
        const int* __restrict__ bstart, const int* __restrict__ bcnt,
        int* __restrict__ offsets, int* __restrict__ csr, int n) {
    __shared__ int ncnt[512], nofs[512], ps[256];
    int g = blockIdx.x;
    int base = bstart[g];
    int cnt = bcnt[g];
    int n0 = g << 9;
    int nr = n - n0; if (nr > 512) nr = 512;
    for (int i = threadIdx.x; i < 512; i += 256) ncnt[i] = 0;
    __syncthreads();
    for (int i = threadIdx.x; i < cnt; i += 256)
        atomicAdd(&ncnt[ebd[base + i] - n0], 1);
    __syncthreads();
    int t = threadIdx.x;
    int c0 = ncnt[2 * t], c1 = ncnt[2 * t + 1];
    ps[t] = c0 + c1;
    __syncthreads();
    for (int off = 1; off < 256; off <<= 1) {
        int u = 0;
        if (t >= off) u = ps[t - off];
        __syncthreads();
        if (t >= off) ps[t] += u;
        __syncthreads();
    }
    int pex = ps[t] - (c0 + c1);
    nofs[2 * t] = pex;
    nofs[2 * t + 1] = pex + c0;
    __syncthreads();
    for (int i = threadIdx.x; i < nr; i += 256)
        offsets[n0 + i] = base + nofs[i];
    for (int i = threadIdx.x; i < 512; i += 256) ncnt[i] = 0;   // reuse as cursor
    __syncthreads();
    for (int i = threadIdx.x; i < cnt; i += 256) {
        int d = ebd[base + i] - n0;
        int p = base + nofs[d] + atomicAdd(&ncnt[d], 1);
        csr[p] = ebs[base + i];
    }
}

// ---------------------------------------------------------------------------
// W preprocessing: stacked [Wl;Wr] transposed to [col][k], split bf16 hi/lo.
__global__ void build_wt(const float* __restrict__ Wa, const float* __restrict__ Wr,
                         __bf16* __restrict__ WtHi, __bf16* __restrict__ WtLo) {
    int idx = blockIdx.x * 256 + threadIdx.x;         // 3*128*256 total
    if (idx >= 3 * 128 * 256) return;
    int L = idx / (128 * 256);
    int rem = idx % (128 * 256);
    int c = rem / 256;
    int k = rem % 256;
    float v = (k < 128) ? Wa[((size_t)L * 128 + k) * 128 + c]
                        : Wr[((size_t)L * 128 + (k - 128)) * 128 + c];
    __bf16 h = (__bf16)v;
    __bf16 l = (__bf16)(v - (float)h);
    WtHi[idx] = h;
    WtLo[idx] = l;
}

// ---------------------------------------------------------------------------
// x fp32 -> bf16 single plane (once, layer-0 input)
__global__ void cvt_x(const float* __restrict__ x, __bf16* __restrict__ a,
                      int total8) {
    int i = blockIdx.x * 256 + threadIdx.x;           // 8 floats per thread
    if (i >= total8) return;
    const float4* p = (const float4*)(x + (size_t)i * 8);
    float4 v0 = p[0], v1 = p[1];
    float vv[8] = {v0.x, v0.y, v0.z, v0.w, v1.x, v1.y, v1.z, v1.w};
    bf16x8 h;
    #pragma unroll
    for (int j = 0; j < 8; ++j) h[j] = (__bf16)vv[j];
    *(bf16x8*)(a + (size_t)i * 8) = h;
}

// ---------------------------------------------------------------------------
// mean aggregation (unchanged from R8): gather bf16 plane, one node per
// 16-lane group, 8x unrolled row gathers, fp32 accumulate.
__global__ __launch_bounds__(256) void agg_mean5(
        const __bf16* __restrict__ act, const int* __restrict__ csr,
        const int* __restrict__ offs, __bf16* __restrict__ mean, int n) {
    int node = (blockIdx.x * blockDim.x + threadIdx.x) >> 4;
    int l8 = (threadIdx.x & 15) << 3;
    if (node >= n) return;
    int beg = offs[node], end = offs[node + 1];
    float acc[8] = {0.f, 0.f, 0.f, 0.f, 0.f, 0.f, 0.f, 0.f};
    int i = beg;
    for (; i + 8 <= end; i += 8) {
        bf16x8 v[8];
        #pragma unroll
        for (int u = 0; u < 8; ++u)
            v[u] = *(const bf16x8*)(act + (size_t)csr[i + u] * D + l8);
        #pragma unroll
        for (int u = 0; u < 8; ++u)
            #pragma unroll
            for (int j = 0; j < 8; ++j) acc[j] += (float)v[u][j];
    }
    for (; i + 4 <= end; i += 4) {
        bf16x8 v[4];
        #pragma unroll
        for (int u = 0; u < 4; ++u)
            v[u] = *(const bf16x8*)(act + (size_t)csr[i + u] * D + l8);
        #pragma unroll
        for (int u = 0; u < 4; ++u)
            #pragma unroll
            for (int j = 0; j < 8; ++j) acc[j] += (float)v[u][j];
    }
    for (; i < end; ++i) {
        bf16x8 v = *(const bf16x8*)(act + (size_t)csr[i] * D + l8);
        #pragma unroll
        for (int j = 0; j < 8; ++j) acc[j] += (float)v[j];
    }
    int deg = end - beg;
    float inv = 1.0f / (float)(deg > 1 ? deg : 1);
    bf16x8 h;
    #pragma unroll
    for (int j = 0; j < 8; ++j) h[j] = (__bf16)(acc[j] * inv);
    *(bf16x8*)(mean + (size_t)node * D + l8) = h;
}

// ---------------------------------------------------------------------------
// MFMA GEMM v7: 512-thread block = 8 waves; block covers one 16-row tile x
// ALL 128 cols (wave w owns cols w*16..+15). A-tile (16 rows x K=256 bf16 =
// 8KB) staged into LDS ONCE per tile (vs gemm6's 8x duplicated global loads),
// double-buffered, XOR-swizzled (byte ^= (row&7)<<4 on 16B chunks) so the
// 16-lane stride-512B ds_read_b128 pattern is conflict-free. W frags stay in
// VGPRs (64/lane). Same verified mfma(W,A) mapping + sC-transpose epilogue.
__global__ __launch_bounds__(512, 4) void sage_gemm7(
        const __bf16* __restrict__ mean, const __bf16* __restrict__ act,
        const __bf16* __restrict__ WtHi, const __bf16* __restrict__ WtLo,
        const float* __restrict__ bias,
        __bf16* __restrict__ oB, float* __restrict__ oF,
        int n, int mode, int ntiles) {
    __shared__ __align__(16) char sA[2][8192];   // [buf][row:512B][k swz]
    __shared__ __align__(16) char sC[8192];      // epilogue transpose tile
    int tid  = threadIdx.x;
    int wave = tid >> 6;
    int lane = tid & 63;
    int r16  = lane & 15;
    int kg   = lane >> 4;
    int colbase = wave * 16;

    // W fragments: this wave's 16 cols, full stacked K, hi+lo (64 VGPR)
    bf16x8 BH[8], BL[8];
    #pragma unroll
    for (int c8 = 0; c8 < 8; ++c8) {
        size_t o = (size_t)(colbase + r16) * 256 + c8 * 32 + kg * 8;
        BH[c8] = *(const bf16x8*)(WtHi + o);
        BL[c8] = *(const bf16x8*)(WtLo + o);
    }
    float4 bv = *(const float4*)(bias + colbase + kg * 4);

    // per-lane swizzled ds_read offsets for the 8 K-chunks
    int xm = (r16 & 7) << 4;
    int kb[8];
    #pragma unroll
    for (int c8 = 0; c8 < 8; ++c8)
        kb[c8] = r16 * 512 + ((c8 * 64 + kg * 16) ^ xm);

    // staging geometry: thread -> (srow, sc16) 16B chunk
    int srow = tid >> 5;           // 0..15
    int sc16 = tid & 31;           // 0..31 (32 x 16B per row)
    int sdst = srow * 512 + ((sc16 * 16) ^ ((srow & 7) << 4));

    auto stage_load = [&](int t, int4& r) {
        int grow = t * 16 + srow;
        if (grow < n) {
            const __bf16* src = (sc16 < 16)
                ? (mean + (size_t)grow * D + sc16 * 8)
                : (act  + (size_t)grow * D + (sc16 - 16) * 8);
            r = *(const int4*)src;
        } else {
            r = make_int4(0, 0, 0, 0);
        }
    };

    int tstride = gridDim.x;
    int t = blockIdx.x;

    int4 sreg = make_int4(0, 0, 0, 0);
    if (t < ntiles) stage_load(t, sreg);
    *(int4*)(sA[0] + sdst) = sreg;
    __syncthreads();
    int cur = 0;

    for (; t < ntiles; t += tstride) {
        int tn = t + tstride;
        bool hasnext = tn < ntiles;
        int4 nreg;
        if (hasnext) stage_load(tn, nreg);

        // compute: 8 swizzled ds_read_b128 + 16 MFMA
        f32x4 acc = (f32x4){0.f, 0.f, 0.f, 0.f};
        const char* base = sA[cur];
        #pragma unroll
        for (int c8 = 0; c8 < 8; ++c8) {
            bf16x8 a = *(const bf16x8*)(base + kb[c8]);
            acc = __builtin_amdgcn_mfma_f32_16x16x32_bf16(BH[c8], a, acc, 0, 0, 0);
            acc = __builtin_amdgcn_mfma_f32_16x16x32_bf16(BL[c8], a, acc, 0, 0, 0);
        }

        __syncthreads();                       // buf[cur] reads + prev sC reads done
        if (hasnext) *(int4*)(sA[cur ^ 1] + sdst) = nreg;

        // epilogue: acc -> sC (row = r16, col = colbase + kg*4 + j)
        float v0 = acc[0] + bv.x;
        float v1 = acc[1] + bv.y;
        float v2 = acc[2] + bv.z;
        float v3 = acc[3] + bv.w;
        if (mode == 0) {
            v0 = fmaxf(v0, 0.f); v1 = fmaxf(v1, 0.f);
            v2 = fmaxf(v2, 0.f); v3 = fmaxf(v3, 0.f);
            bf16x4 h4;
            h4[0] = (__bf16)v0; h4[1] = (__bf16)v1;
            h4[2] = (__bf16)v2; h4[3] = (__bf16)v3;
            *(bf16x4*)(sC + r16 * 256 + (colbase + kg * 4) * 2) = h4;
        } else {
            *(f32x4*)(sC + r16 * 512 + (colbase + kg * 4) * 4) =
                (f32x4){v0, v1, v2, v3};
        }
        __syncthreads();

        // cooperative coalesced store of the 16x128 tile
        if (mode == 0) {
            if (tid < 256) {
                int rr = tid >> 4, c16 = tid & 15;
                int grow = t * 16 + rr;
                if (grow < n) {
                    int4 h = *(const int4*)(sC + rr * 256 + c16 * 16);
                    *(int4*)(oB + (size_t)grow * D + c16 * 8) = h;
                }
            }
        } else {
            int rr = tid >> 5, c = tid & 31;
            int grow = t * 16 + rr;
            if (grow < n) {
                f32x4 f = *(const f32x4*)(sC + rr * 512 + c * 16);
                *(f32x4*)(oF + (size_t)grow * D + c * 4) = f;
            }
        }
        cur ^= 1;
    }
}

// ---------------------------------------------------------------------------
extern "C" void kernel_launch(void* const* d_in, const int* in_sizes, int n_in,
                              void* d_out, int out_size, void* d_ws, size_t ws_size,
                              hipStream_t stream) {
    const float* x  = (const float*)d_in[0];
    const void*  ei = d_in[1];
    const float* Wa = (const float*)d_in[2];   // [3,128,128]
    const float* Wr = (const float*)d_in[3];   // [3,128,128]
    const float* bb = (const float*)d_in[4];   // [3,128]
    float* outp = (float*)d_out;

    int n  = in_sizes[0] / D;          // 100000
    int nE = in_sizes[1] / 2;          // 1600000
    int G  = (n + 511) >> 9;           // 512-node buckets

    char* ws = (char*)d_ws;
    size_t off = 0;
    auto alloc = [&](size_t bytes) -> char* {
        char* p = ws + off;
        off = (off + bytes + 255) & ~(size_t)255;
        return p;
    };
    int* flag      = (int*)alloc(4);
    int* src32     = (int*)alloc((size_t)nE * 4);
    int* dst32     = (int*)alloc((size_t)nE * 4);
    int* offsets   = (int*)alloc(((size_t)n + 1) * 4);
    int* csr_src   = (int*)alloc((size_t)nE * 4);
    int* ebs       = (int*)alloc((size_t)nE * 4);
    int* ebd       = (int*)alloc((size_t)nE * 4);
    int* bcnt      = (int*)alloc(1024);
    int* bstart    = (int*)alloc(1024);
    int* bcur      = (int*)alloc(1024);
    __bf16* actA   = (__bf16*)alloc((size_t)n * D * 2);
    __bf16* actB   = (__bf16*)alloc((size_t)n * D * 2);
    __bf16* meanP  = (__bf16*)alloc((size_t)n * D * 2);
    __bf16* WtHi   = (__bf16*)alloc((size_t)3 * 128 * 256 * 2);
    __bf16* WtLo   = (__bf16*)alloc((size_t)3 * 128 * 256 * 2);
    (void)ws_size; (void)n_in; (void)out_size;

    const int B = 256;
    int ge = (nE + B - 1) / B;

    // 1) index probe + conversion + W transpose/split + x convert
    hipLaunchKernelGGL(detect_idx, dim3(1), dim3(64), 0, stream, ei, flag, n);
    hipLaunchKernelGGL(convert_idx, dim3(ge), dim3(B), 0, stream,
                       ei, flag, src32, dst32, nE);
    hipLaunchKernelGGL(build_wt, dim3(384), dim3(256), 0, stream, Wa, Wr, WtHi, WtLo);
    int total8 = n * D / 8;
    hipLaunchKernelGGL(cvt_x, dim3((total8 + 255) / 256), dim3(256), 0, stream,
                       x, actA, total8);

    // 2) bucketed CSR build
    hipMemsetAsync(bcnt, 0, 1024, stream);
    hipLaunchKernelGGL(bucket_hist, dim3(512), dim3(B), 0, stream, dst32, bcnt, nE);
    hipLaunchKernelGGL(bucket_scan, dim3(1), dim3(B), 0, stream,
                       bcnt, bstart, bcur, G, nE, offsets, n);
    hipLaunchKernelGGL(bucket_fill, dim3((nE + CHUNK - 1) / CHUNK), dim3(B), 0, stream,
                       src32, dst32, bcur, ebs, ebd, nE);
    hipLaunchKernelGGL(bucket_scatter, dim3(G), dim3(B), 0, stream,
                       ebs, ebd, bstart, bcnt, offsets, csr_src, n);

    // 3) layers (ping-pong actA <-> actB; mean buffer reused)
    int agg_blocks = (n * 16 + B - 1) / B;
    int ntiles = (n + 15) / 16;
    int gemm_grid = 512;               // 2 blocks/CU at 512 threads
    const int WSTRIDE = 128 * 256;

    // layer 0: actA -> actB (ReLU, bf16)
    hipLaunchKernelGGL(agg_mean5, dim3(agg_blocks), dim3(B), 0, stream,
                       actA, csr_src, offsets, meanP, n);
    hipLaunchKernelGGL(sage_gemm7, dim3(gemm_grid), dim3(512), 0, stream,
                       meanP, actA, WtHi + 0 * WSTRIDE, WtLo + 0 * WSTRIDE,
                       bb + 0 * D, actB, outp, n, 0, ntiles);

    // layer 1: actB -> actA (ReLU, bf16)
    hipLaunchKernelGGL(agg_mean5, dim3(agg_blocks), dim3(B), 0, stream,
                       actB, csr_src, offsets, meanP, n);
    hipLaunchKernelGGL(sage_gemm7, dim3(gemm_grid), dim3(512), 0, stream,
                       meanP, actB, WtHi + 1 * WSTRIDE, WtLo + 1 * WSTRIDE,
                       bb + 1 * D, actA, outp, n, 0, ntiles);

    // layer 2: actA -> d_out (no ReLU, fp32)
    hipLaunchKernelGGL(agg_mean5, dim3(agg_blocks), dim3(B), 0, stream,
                       actA, csr_src, offsets, meanP, n);
    hipLaunchKernelGGL(sage_gemm7, dim3(gemm_grid), dim3(512), 0, stream,
                       meanP, actA, WtHi + 2 * WSTRIDE, WtLo + 2 * WSTRIDE,
                       bb + 2 * D, actB, outp, n, 1, ntiles);
}